// Round 14
// baseline (3227.975 us; speedup 1.0000x reference)
//
#include <hip/hip_runtime.h>
#include <hip/hip_bf16.h>
#include <cstdio>

#define INV2 0.70710678118654752440f
typedef __hip_bfloat16 bf16;
typedef __attribute__((ext_vector_type(8))) short short8v;
typedef __attribute__((ext_vector_type(8))) unsigned short u16x8;
typedef __attribute__((ext_vector_type(4))) float f32x4;

__device__ __forceinline__ float silu_f(float v) { return v / (1.0f + __expf(-v)); }
__device__ __forceinline__ float bf2f(unsigned short u) {
    union { unsigned int i; float f; } t; t.i = ((unsigned int)u) << 16; return t.f;
}
__device__ __forceinline__ unsigned short f2bf(float x) {
    bf16 b = __float2bfloat16(x);
    return *reinterpret_cast<unsigned short*>(&b);
}
__device__ __forceinline__ float toF(float v) { return v; }
__device__ __forceinline__ float toF(bf16 v) { return __bfloat162float(v); }
__device__ __forceinline__ void stF(float* p, float v) { *p = v; }
__device__ __forceinline__ void stF(bf16* p, float v) { *p = __float2bfloat16(v); }

__device__ __forceinline__ void ld8f(const float* p, float* o) {
    const float4 a = ((const float4*)p)[0], b = ((const float4*)p)[1];
    o[0]=a.x; o[1]=a.y; o[2]=a.z; o[3]=a.w; o[4]=b.x; o[5]=b.y; o[6]=b.z; o[7]=b.w;
}
__device__ __forceinline__ void ld8f(const bf16* p, float* o) {
    const u16x8 u = *(const u16x8*)p;
#pragma unroll
    for (int j = 0; j < 8; j++) o[j] = bf2f(u[j]);
}

// async global->LDS, 16B per lane
__device__ __forceinline__ void gll16(const void* g, void* l) {
    __builtin_amdgcn_global_load_lds(
        (const __attribute__((address_space(1))) unsigned int*)g,
        (__attribute__((address_space(3))) unsigned int*)l, 16, 0, 0);
}

enum { AM_NORMAL = 0, AM_MUL2 = 1, AM_GATHER = 2, AM_SILU = 3, AM_DMA = 4 };
enum { EP_PLAIN = 0, EP_SILU = 1, EP_ACCUM = 2, EP_RES2 = 3, EP_RESADD = 4, EP_HEADRES = 5 };

__device__ __forceinline__ float epi_val(int EPI, float v, float c, float x) {
    if (EPI == EP_PLAIN)   return v;
    if (EPI == EP_SILU)    return silu_f(v);
    if (EPI == EP_ACCUM)   return c + v;
    if (EPI == EP_RES2)    return (c + silu_f(v)) * INV2;
    if (EPI == EP_RESADD)  return c + (x + silu_f(v)) * INV2;
    /* EP_HEADRES */       return (silu_f(x) + silu_f(v)) * INV2;
}

// ---------------- R7 mgemm (256 threads) for N<=128 outputs ----------------
template <int AMODE, int EPI, int BN, typename AT, typename CT>
__global__ __launch_bounds__(256) void mgemm(
    const AT* __restrict__ A, const AT* __restrict__ A2,
    const int* __restrict__ gs, const int* __restrict__ gt,
    const bf16* __restrict__ Bt,
    CT* __restrict__ C, const CT* __restrict__ X,
    int Mrows, int Ncols, int K)
{
    constexpr bool DMA = (AMODE == AM_DMA);
    constexpr int AST = DMA ? 32 : 40;
    constexpr int FM = (BN == 128) ? 4 : 2;
    __shared__ __align__(16) unsigned short Als[128 * AST];
    __shared__ __align__(16) unsigned short Bls[BN * 32];
    const int tid = threadIdx.x;
    const int row0 = blockIdx.x * 128, col0 = blockIdx.y * BN;

    const int sr = tid >> 1;
    const int sh = (tid & 1) * 16;
    const int gr = row0 + sr;
    const bool rok = (gr < Mrows);
    int is_ = 0, it_ = 0;
    if (AMODE == AM_GATHER) { if (rok) { is_ = gs[gr]; it_ = gt[gr]; } }

    const int l = tid & 63, wid = tid >> 6;
    const int lr = l & 15;
    const int lk = (l >> 4) * 8;
    const int wrow = (BN == 128) ? ((wid & 1) * 64) : (wid * 32);
    const int wcol = (BN == 128) ? ((wid >> 1) * 64) : 0;

    f32x4 acc[FM][4];
#pragma unroll
    for (int i = 0; i < FM; i++)
#pragma unroll
        for (int j = 0; j < 4; j++)
#pragma unroll
            for (int q = 0; q < 4; q++) acc[i][j][q] = 0.f;

    for (int k0 = 0; k0 < K; k0 += 32) {
        if constexpr (DMA) {
#pragma unroll
            for (int i = 0; i < 2; i++) {
                const int c = i * 256 + tid;
                const int row = c >> 2;
                if (row0 + row < Mrows)
                    gll16(A + (size_t)(row0 + row) * K + k0 + (c & 3) * 8, &Als[c * 8]);
            }
        } else {
            float va[16];
            if (rok) {
                if (AMODE == AM_GATHER) {
                    const int reg = k0 >> 7, koff = (k0 & 127) + sh;
                    const AT* src = (reg == 0) ? (A + (size_t)is_ * 128 + koff)
                                  : (reg == 1) ? (A + (size_t)it_ * 128 + koff)
                                               : (A2 + (size_t)gr * 128 + koff);
                    ld8f(src, va); ld8f(src + 8, va + 8);
                } else {
                    const AT* src = A + (size_t)gr * K + k0 + sh;
                    ld8f(src, va); ld8f(src + 8, va + 8);
                    if (AMODE == AM_MUL2) {
                        float vb[16];
                        const AT* s2 = A2 + (size_t)gr * K + k0 + sh;
                        ld8f(s2, vb); ld8f(s2 + 8, vb + 8);
#pragma unroll
                        for (int j = 0; j < 16; j++) va[j] *= vb[j];
                    } else if (AMODE == AM_SILU) {
#pragma unroll
                        for (int j = 0; j < 16; j++) va[j] = silu_f(va[j]);
                    }
                }
            } else {
#pragma unroll
                for (int j = 0; j < 16; j++) va[j] = 0.f;
            }
            u16x8 av0, av1;
#pragma unroll
            for (int j = 0; j < 8; j++) { av0[j] = f2bf(va[j]); av1[j] = f2bf(va[j + 8]); }
            *(u16x8*)&Als[sr * AST + sh] = av0;
            *(u16x8*)&Als[sr * AST + sh + 8] = av1;
        }

#pragma unroll
        for (int i = 0; i < BN / 64; i++) {
            const int c = i * 256 + tid;
            gll16(Bt + (size_t)(col0 + (c >> 2)) * K + k0 + (c & 3) * 8, &Bls[c * 8]);
        }

        __syncthreads();

        short8v af[FM], bfr[4];
#pragma unroll
        for (int fm = 0; fm < FM; fm++)
            af[fm] = *(const short8v*)&Als[(wrow + fm * 16 + lr) * AST + lk];
#pragma unroll
        for (int fn = 0; fn < 4; fn++)
            bfr[fn] = *(const short8v*)&Bls[(wcol + fn * 16 + lr) * 32 + lk];
#pragma unroll
        for (int fm = 0; fm < FM; fm++)
#pragma unroll
            for (int fn = 0; fn < 4; fn++)
                acc[fm][fn] = __builtin_amdgcn_mfma_f32_16x16x32_bf16(
                    af[fm], bfr[fn], acc[fm][fn], 0, 0, 0);

        __syncthreads();
    }

#pragma unroll
    for (int fm = 0; fm < FM; fm++) {
        const int rb = row0 + wrow + fm * 16 + (l >> 4) * 4;
#pragma unroll
        for (int fn = 0; fn < 4; fn++) {
            const int c = col0 + wcol + fn * 16 + lr;
#pragma unroll
            for (int r = 0; r < 4; r++) {
                const int rr = rb + r;
                if (rr >= Mrows) continue;
                const size_t o = (size_t)rr * Ncols + c;
                stF(&C[o], epi_val(EPI, acc[fm][fn][r],
                                   (EPI >= EP_ACCUM) ? toF(C[o]) : 0.f,
                                   (EPI == EP_RESADD || EPI == EP_HEADRES) ? toF(X[o]) : 0.f));
            }
        }
    }
}

// ---------------- wide mgemm2: BM=128 x BN=256, 512 threads (8 waves) ----------------
template <int AMODE, int EPI, typename AT, typename CT>
__global__ __launch_bounds__(512) void mgemm2(
    const AT* __restrict__ A, const AT* __restrict__ A2,
    const int* __restrict__ gs, const int* __restrict__ gt,
    const bf16* __restrict__ Bt,
    CT* __restrict__ C, const CT* __restrict__ X,
    int Mrows, int K)
{
    constexpr bool DMA = (AMODE == AM_DMA);
    constexpr int AST = DMA ? 32 : 40;
    __shared__ __align__(16) unsigned short Als[2][128 * AST];
    __shared__ __align__(16) unsigned short Bls[2][256 * 32];
    const int tid = threadIdx.x;
    const int row0 = blockIdx.x * 128;

    const int sr = tid >> 2;
    const int sh = (tid & 3) * 8;
    const int gr = row0 + sr;
    const bool rok = (gr < Mrows);
    int is_ = 0, it_ = 0;
    if (AMODE == AM_GATHER) { if (rok) { is_ = gs[gr]; it_ = gt[gr]; } }

    const int l = tid & 63, wid = tid >> 6;
    const int lr = l & 15;
    const int lk = (l >> 4) * 8;
    const int wrow = (wid & 1) * 64;
    const int wcol = (wid >> 1) * 64;

    f32x4 acc[4][4];
#pragma unroll
    for (int i = 0; i < 4; i++)
#pragma unroll
        for (int j = 0; j < 4; j++)
#pragma unroll
            for (int q = 0; q < 4; q++) acc[i][j][q] = 0.f;

    auto loadA = [&](int kk, float* va) {
        if (rok) {
            if (AMODE == AM_GATHER) {
                const int reg = kk >> 7, koff = (kk & 127) + sh;
                const AT* src = (reg == 0) ? (A + (size_t)is_ * 128 + koff)
                              : (reg == 1) ? (A + (size_t)it_ * 128 + koff)
                                           : (A2 + (size_t)gr * 128 + koff);
                ld8f(src, va);
            } else {
                ld8f(A + (size_t)gr * K + kk + sh, va);
                if (AMODE == AM_MUL2) {
                    float vb[8];
                    ld8f(A2 + (size_t)gr * K + kk + sh, vb);
#pragma unroll
                    for (int j = 0; j < 8; j++) va[j] *= vb[j];
                } else if (AMODE == AM_SILU) {
#pragma unroll
                    for (int j = 0; j < 8; j++) va[j] = silu_f(va[j]);
                }
            }
        } else {
#pragma unroll
            for (int j = 0; j < 8; j++) va[j] = 0.f;
        }
    };

    for (int k0 = 0; k0 < K; k0 += 64) {
        float va0[8], va1[8];
#pragma unroll
        for (int h = 0; h < 2; h++) {
            const int kk = k0 + h * 32;
            if constexpr (DMA) {
                const int row = tid >> 2;
                if (row0 + row < Mrows)
                    gll16(A + (size_t)(row0 + row) * K + kk + (tid & 3) * 8, &Als[h][tid * 8]);
            } else {
                loadA(kk, h ? va1 : va0);
            }
#pragma unroll
            for (int i = 0; i < 2; i++) {
                const int c = i * 512 + tid;
                gll16(Bt + (size_t)(c >> 2) * K + kk + (c & 3) * 8, &Bls[h][c * 8]);
            }
        }
        if constexpr (!DMA) {
            u16x8 av0, av1;
#pragma unroll
            for (int j = 0; j < 8; j++) { av0[j] = f2bf(va0[j]); av1[j] = f2bf(va1[j]); }
            *(u16x8*)&Als[0][sr * AST + sh] = av0;
            *(u16x8*)&Als[1][sr * AST + sh] = av1;
        }

        __syncthreads();

#pragma unroll
        for (int h = 0; h < 2; h++) {
            short8v af[4], bfr[4];
#pragma unroll
            for (int fm = 0; fm < 4; fm++)
                af[fm] = *(const short8v*)&Als[h][(wrow + fm * 16 + lr) * AST + lk];
#pragma unroll
            for (int fn = 0; fn < 4; fn++)
                bfr[fn] = *(const short8v*)&Bls[h][(wcol + fn * 16 + lr) * 32 + lk];
#pragma unroll
            for (int fm = 0; fm < 4; fm++)
#pragma unroll
                for (int fn = 0; fn < 4; fn++)
                    acc[fm][fn] = __builtin_amdgcn_mfma_f32_16x16x32_bf16(
                        af[fm], bfr[fn], acc[fm][fn], 0, 0, 0);
        }

        __syncthreads();
    }

#pragma unroll
    for (int fm = 0; fm < 4; fm++) {
        const int rb = row0 + wrow + fm * 16 + (l >> 4) * 4;
#pragma unroll
        for (int fn = 0; fn < 4; fn++) {
            const int c = wcol + fn * 16 + lr;
#pragma unroll
            for (int r = 0; r < 4; r++) {
                const int rr = rb + r;
                if (rr >= Mrows) continue;
                const size_t o = (size_t)rr * 256 + c;
                stF(&C[o], epi_val(EPI, acc[fm][fn][r],
                                   (EPI >= EP_ACCUM) ? toF(C[o]) : 0.f,
                                   (EPI == EP_RESADD || EPI == EP_HEADRES) ? toF(X[o]) : 0.f));
            }
        }
    }
}

// ---------------- rgemm: A panel in REGISTERS (one HBM trip per block) ----------------
// bf16 [M,256] @ [256,256]: BM=128 x BN=256, 8 waves as 4(row)x2(col);
// wave owns 32 rows x 128 cols, FM=2, FN=8. A loaded once into areg[2][8].
template <int EPI>
__global__ __launch_bounds__(512) void rgemm(
    const bf16* __restrict__ A, const bf16* __restrict__ Bt,
    bf16* __restrict__ C, const bf16* __restrict__ X, int Mrows)
{
    __shared__ __align__(16) unsigned short Bls[2][256 * 32];  // 32 KB dbuf
    const int tid = threadIdx.x;
    const int row0 = blockIdx.x * 128;
    const int l = tid & 63, wv = tid >> 6;
    const int lr = l & 15, lg = l >> 4, lk = lg * 8;
    const int wr = (wv & 3) * 32;      // wave row offset in tile
    const int wc = (wv >> 2) * 128;    // wave col offset

    // ---- load full A panel into registers (16 independent dwordx4) ----
    u16x8 areg[2][8];
#pragma unroll
    for (int fm = 0; fm < 2; fm++) {
        int row = row0 + wr + fm * 16 + lr;
        if (row >= Mrows) row = Mrows - 1;   // clamp; epilogue skips OOB rows
        const bf16* ap = A + (size_t)row * 256 + lk;
#pragma unroll
        for (int ks = 0; ks < 8; ks++)
            areg[fm][ks] = *(const u16x8*)(ap + ks * 32);
    }

    f32x4 acc[2][8];
#pragma unroll
    for (int i = 0; i < 2; i++)
#pragma unroll
        for (int j = 0; j < 8; j++)
#pragma unroll
            for (int q = 0; q < 4; q++) acc[i][j][q] = 0.f;

    auto stageB = [&](int buf, int kk) {
#pragma unroll
        for (int i = 0; i < 2; i++) {
            const int c = i * 512 + tid;       // [0,1024): col=c>>2, k-chunk=(c&3)*8
            gll16(Bt + (size_t)(c >> 2) * 256 + kk + (c & 3) * 8, &Bls[buf][c * 8]);
        }
    };

    for (int kp = 0; kp < 4; kp++) {
        stageB(0, kp * 64);
        stageB(1, kp * 64 + 32);
        __syncthreads();
#pragma unroll
        for (int h = 0; h < 2; h++) {
            short8v bfr[8];
#pragma unroll
            for (int fn = 0; fn < 8; fn++)
                bfr[fn] = *(const short8v*)&Bls[h][(wc + fn * 16 + lr) * 32 + lk];
#pragma unroll
            for (int fm = 0; fm < 2; fm++) {
                const short8v av = (short8v)areg[fm][kp * 2 + h];
#pragma unroll
                for (int fn = 0; fn < 8; fn++)
                    acc[fm][fn] = __builtin_amdgcn_mfma_f32_16x16x32_bf16(
                        av, bfr[fn], acc[fm][fn], 0, 0, 0);
            }
        }
        __syncthreads();
    }

    // ---- epilogue ----
#pragma unroll
    for (int fm = 0; fm < 2; fm++) {
        const int rb = row0 + wr + fm * 16 + lg * 4;
#pragma unroll
        for (int fn = 0; fn < 8; fn++) {
            const int c = wc + fn * 16 + lr;
#pragma unroll
            for (int q = 0; q < 4; q++) {
                const int rr = rb + q;
                if (rr >= Mrows) continue;
                const size_t o = (size_t)rr * 256 + c;
                stF(&C[o], epi_val(EPI, acc[fm][fn][q],
                                   (EPI >= EP_ACCUM) ? toF(C[o]) : 0.f,
                                   (EPI == EP_HEADRES) ? toF(X[o]) : 0.f));
            }
        }
    }
}

// ---------------- fused triplet GEMM ----------------
__global__ __launch_bounds__(256) void trip_gemm(
    const bf16* __restrict__ x,     // [E,64]
    const bf16* __restrict__ cb,    // [T,16]
    const int* __restrict__ ba, const int* __restrict__ ca,
    const bf16* __restrict__ BtT,   // [64][1024]
    float* __restrict__ agg)
{
    __shared__ __align__(16) unsigned short At[128 * 40];
    __shared__ __align__(16) unsigned short Bs[64 * 40];
    const int tid = threadIdx.x;
    const int gr0 = blockIdx.x * 128;

    const int sr = tid >> 1, sh = tid & 1;
    const int gr = gr0 + sr;
    const int e = ba[gr];
    float xr[32];
    {
        const bf16* xp = x + (size_t)e * 64 + sh * 16;
        const u16x8 a0 = *(const u16x8*)xp;
        const u16x8 a1 = *(const u16x8*)(xp + 8);
        const u16x8 b0 = *(const u16x8*)(xp + 32);
        const u16x8 b1 = *(const u16x8*)(xp + 40);
#pragma unroll
        for (int j = 0; j < 8; j++) {
            xr[j] = bf2f(a0[j]); xr[8 + j] = bf2f(a1[j]);
            xr[16 + j] = bf2f(b0[j]); xr[24 + j] = bf2f(b1[j]);
        }
    }
    float cbr[16];
    {
        const u16x8 c0 = *(const u16x8*)(cb + (size_t)gr * 16);
        const u16x8 c1 = *(const u16x8*)(cb + (size_t)gr * 16 + 8);
#pragma unroll
        for (int j = 0; j < 8; j++) { cbr[j] = bf2f(c0[j]); cbr[8 + j] = bf2f(c1[j]); }
    }

    const int l = tid & 63, wv = tid >> 6;
    const int lr = l & 15, lg = l >> 4, lk = lg * 8;
    const int wrow = wv * 32;
    const int bcol = tid >> 2, bq = tid & 3;

    f32x4 acc[2][4];
#pragma unroll
    for (int i = 0; i < 2; i++)
#pragma unroll
        for (int j = 0; j < 4; j++)
#pragma unroll
            for (int q = 0; q < 4; q++) acc[i][j][q] = 0.f;

#pragma unroll 4
    for (int ks = 0; ks < 32; ++ks) {
        const float cbv = cbr[ks >> 1];
        const int ib = (ks & 1) * 16;
        u16x8 p0, p1;
#pragma unroll
        for (int j = 0; j < 8; j++) {
            p0[j] = f2bf(cbv * xr[ib + j]);
            p1[j] = f2bf(cbv * xr[ib + 8 + j]);
        }
        *(u16x8*)&At[sr * 40 + sh * 16] = p0;
        *(u16x8*)&At[sr * 40 + sh * 16 + 8] = p1;
        const u16x8 bv8 = *(const u16x8*)(BtT + (size_t)bcol * 1024 + ks * 32 + bq * 8);
        *(u16x8*)&Bs[bcol * 40 + bq * 8] = bv8;
        __syncthreads();

        short8v af[2], bf4[4];
        af[0] = *(const short8v*)&At[(wrow + lr) * 40 + lk];
        af[1] = *(const short8v*)&At[(wrow + 16 + lr) * 40 + lk];
#pragma unroll
        for (int fn = 0; fn < 4; fn++)
            bf4[fn] = *(const short8v*)&Bs[(fn * 16 + lr) * 40 + lk];
#pragma unroll
        for (int fm = 0; fm < 2; fm++)
#pragma unroll
            for (int fn = 0; fn < 4; fn++)
                acc[fm][fn] = __builtin_amdgcn_mfma_f32_16x16x32_bf16(
                    af[fm], bf4[fn], acc[fm][fn], 0, 0, 0);
        __syncthreads();
    }

#pragma unroll
    for (int fm = 0; fm < 2; fm++)
#pragma unroll
        for (int q = 0; q < 4; q++) {
            const int rr = wrow + fm * 16 + lg * 4 + q;
            const int eo = ca[gr0 + rr];
#pragma unroll
            for (int fn = 0; fn < 4; fn++)
                atomicAdd(&agg[(size_t)eo * 64 + fn * 16 + lr], acc[fm][fn][q]);
        }
}

__global__ __launch_bounds__(256) void cb16(const float* __restrict__ cbf,
                                            const float* __restrict__ Wcb,
                                            bf16* __restrict__ cb, int T)
{
    const int gid = blockIdx.x * 256 + threadIdx.x;
    const int t = gid >> 4, c = gid & 15;
    if (t >= T) return;
    const float* cr = cbf + (size_t)t * 7;
    float s = 0.f;
#pragma unroll
    for (int k = 0; k < 7; k++) s += cr[k] * Wcb[k * 16 + c];
    cb[(size_t)t * 16 + c] = __float2bfloat16(s);
}

struct TJob { const float* src; bf16* dst; int K; int N; };
struct TJobs { TJob j[40]; };

__global__ __launch_bounds__(256) void transpose_weights(TJobs JB) {
    const TJob J = JB.j[blockIdx.y];
    const int total = J.K * J.N;
    const int gid = blockIdx.x * 256 + threadIdx.x;
    if (gid >= total) return;
    const int n = gid / J.K, k = gid - n * J.K;
    J.dst[(size_t)n * J.K + k] = __float2bfloat16(J.src[(size_t)k * J.N + n]);
}

__global__ __launch_bounds__(256) void embed_h(const int* __restrict__ z,
                                               const float* __restrict__ tab,
                                               float* __restrict__ h, int N)
{
    const int gid = blockIdx.x * 256 + threadIdx.x;
    const int n = gid >> 7, j = gid & 127;
    if (n >= N) return;
    h[(size_t)n * 128 + j] = tab[(size_t)z[n] * 128 + j];
}

__global__ __launch_bounds__(256) void scatter_ha(const bf16* __restrict__ xa,
                                                  const int* __restrict__ idxt,
                                                  float* __restrict__ ha, int E)
{
    const int gid = blockIdx.x * 256 + threadIdx.x;
    const int e = gid >> 7, j = gid & 127;
    if (e >= E) return;
    atomicAdd(&ha[(size_t)idxt[e] * 128 + j], toF(xa[(size_t)e * 128 + j]));
}

template <typename AT>
__global__ __launch_bounds__(256) void rowdot(const AT* __restrict__ Xm,
                                              const float* __restrict__ w,
                                              float* __restrict__ outv,
                                              int rows, int width, int ostride)
{
    const int wid = (blockIdx.x * 256 + threadIdx.x) >> 6;
    const int lane = threadIdx.x & 63;
    if (wid >= rows) return;
    float s = 0.f;
    for (int q = lane; q < width; q += 64) s += toF(Xm[(size_t)wid * width + q]) * w[q];
#pragma unroll
    for (int off = 32; off > 0; off >>= 1) s += __shfl_down(s, off);
    if (lane == 0) outv[(size_t)wid * ostride] = s;
}

__global__ __launch_bounds__(256) void scatter_forces(const float* __restrict__ Fe,
                                                      const float* __restrict__ Vst,
                                                      const int* __restrict__ idxt,
                                                      float* __restrict__ out, int E)
{
    const int e = blockIdx.x * 256 + threadIdx.x;
    if (e >= E) return;
    const float f = Fe[e];
    const int n = idxt[e];
    atomicAdd(&out[(size_t)n * 4 + 1], f * Vst[(size_t)e * 3 + 0]);
    atomicAdd(&out[(size_t)n * 4 + 2], f * Vst[(size_t)e * 3 + 1]);
    atomicAdd(&out[(size_t)n * 4 + 3], f * Vst[(size_t)e * 3 + 2]);
}

#define MG(AM, EP, BNv, Aptr, A2p, GS, GT, Btp, Cp, Xp, MR, NC, KK)                       \
    mgemm<AM, EP, BNv><<<dim3(((MR) + 127) / 128, (NC) / (BNv)), 256, 0, stream>>>(       \
        Aptr, A2p, GS, GT, Btp, Cp, Xp, MR, NC, KK)

#define MG2(AM, EP, Aptr, A2p, GS, GT, Btp, Cp, Xp, MR, KK)                               \
    mgemm2<AM, EP><<<((MR) + 127) / 128, 512, 0, stream>>>(                               \
        Aptr, A2p, GS, GT, Btp, Cp, Xp, MR, KK)

#define RG(EP, Aptr, Btp, Cp, Xp, MR)                                                     \
    rgemm<EP><<<((MR) + 127) / 128, 512, 0, stream>>>(Aptr, Btp, Cp, Xp, MR)

extern "C" void kernel_launch(void* const* d_in, const int* in_sizes, int n_in,
                              void* d_out, int out_size, void* d_ws, size_t ws_size,
                              hipStream_t stream)
{
    const int N = in_sizes[0];
    const int E = in_sizes[1];
    const int T = in_sizes[3];
    const int NB = 2;

    const int*   z        = (const int*)d_in[0];
    const int*   idx_s    = (const int*)d_in[1];
    const int*   idx_t    = (const int*)d_in[2];
    const int*   id3_ba   = (const int*)d_in[3];
    const int*   id3_ca   = (const int*)d_in[4];
    const float* rbf      = (const float*)d_in[5];
    const float* cbf      = (const float*)d_in[6];
    const float* V_st     = (const float*)d_in[7];
    const float* atom_tab = (const float*)d_in[8];
    const float* W_edge_in= (const float*)d_in[9];
    const float* rbf_w3   = (const float*)d_in[10];
    const float* W_down   = (const float*)d_in[11];
    const float* W_cbf    = (const float*)d_in[12];
    const float* W_bil    = (const float*)d_in[13];
    const float* W_up     = (const float*)d_in[14];
    const float* W_res_e  = (const float*)d_in[15];
    const float* rbf_wh   = (const float*)d_in[16];
    const float* W_e2a    = (const float*)d_in[17];
    const float* W_res_a  = (const float*)d_in[18];
    const float* W_outE_in  = (const float*)d_in[19];
    const float* W_outE_res = (const float*)d_in[20];
    const float* W_outE_fin = (const float*)d_in[21];
    const float* W_outF_in  = (const float*)d_in[22];
    const float* W_outF_res = (const float*)d_in[23];
    const float* W_outF_fin = (const float*)d_in[24];

    float* out = (float*)d_out;

    // ---- workspace layout ----
    char* base = (char*)d_ws;
    size_t off = 0;
    auto alloc = [&](size_t nbytes) { char* p = base + off; off += (nbytes + 15) & ~(size_t)15; return p; };
    bf16*  m_cur = (bf16*)alloc((size_t)E * 256 * 2);
    bf16*  headF = (bf16*)alloc((size_t)E * 256 * 2);
    bf16*  S1    = (bf16*)alloc((size_t)E * 256 * 2);
    float* agg   = (float*)alloc((size_t)E * 64 * 4);
    bf16*  xbuf  = (bf16*)alloc((size_t)E * 64 * 2);
    float* h_cur = (float*)alloc((size_t)N * 128 * 4);
    float* headE = (float*)alloc((size_t)N * 128 * 4);
    float* ha    = (float*)alloc((size_t)N * 128 * 4);
    float* tA    = (float*)alloc((size_t)N * 128 * 4);
    bf16 *bt_outF[3], *bt_outE[3], *bt_r3[2], *bt_down[2], *bt_bilT[2], *bt_up[2],
         *bt_rese[8], *bt_rh[2], *bt_e2a[2], *bt_resa[4], *bt_Fres[2], *bt_Eres[2];
    bf16* bt_edge = (bf16*)alloc(384 * 256 * 2);
    for (int s = 0; s < 3; s++) bt_outF[s] = (bf16*)alloc(256 * 256 * 2);
    for (int s = 0; s < 3; s++) bt_outE[s] = (bf16*)alloc(128 * 128 * 2);
    for (int b = 0; b < 2; b++) bt_r3[b]   = (bf16*)alloc(256 * 128 * 2);
    for (int b = 0; b < 2; b++) bt_down[b] = (bf16*)alloc(64 * 256 * 2);
    for (int b = 0; b < 2; b++) bt_bilT[b] = (bf16*)alloc(64 * 1024 * 2);
    for (int b = 0; b < 2; b++) bt_up[b]   = (bf16*)alloc(256 * 64 * 2);
    for (int i = 0; i < 8; i++) bt_rese[i] = (bf16*)alloc(256 * 256 * 2);
    for (int b = 0; b < 2; b++) bt_rh[b]   = (bf16*)alloc(256 * 128 * 2);
    for (int b = 0; b < 2; b++) bt_e2a[b]  = (bf16*)alloc(128 * 256 * 2);
    for (int i = 0; i < 4; i++) bt_resa[i] = (bf16*)alloc(128 * 128 * 2);
    for (int i = 0; i < 2; i++) bt_Fres[i] = (bf16*)alloc(256 * 256 * 2);
    for (int i = 0; i < 2; i++) bt_Eres[i] = (bf16*)alloc(128 * 128 * 2);
    if (off > ws_size) {
        fprintf(stderr, "kernel_launch: ws too small: need %zu have %zu\n", off, ws_size);
        return;
    }
    bf16*  xa = (bf16*)agg;    // [E,128] bf16, agg region reused post-triplet
    float* Fe = (float*)xbuf;  // [E] f32 post-loop
    float* xE = ha;            // [N,128] f32 post-loop
    bf16*  cbS = S1;           // [T,16] bf16 during triplet

    const float* nfp = nullptr;
    const bf16*  nbp = nullptr;
    const int*   nip = nullptr;

    // ---- weight transposes ----
    {
        TJobs JB; int nj = 0;
        auto addj = [&](const float* s, bf16* d, int K, int Nn) { JB.j[nj++] = TJob{s, d, K, Nn}; };
        addj(W_edge_in, bt_edge, 384, 256);
        for (int s = 0; s < 3; s++) addj(W_outF_in + (size_t)s * 256 * 256, bt_outF[s], 256, 256);
        for (int s = 0; s < 3; s++) addj(W_outE_in + (size_t)s * 128 * 128, bt_outE[s], 128, 128);
        for (int b = 0; b < 2; b++) addj(rbf_w3 + (size_t)b * 128 * 256, bt_r3[b], 128, 256);
        for (int b = 0; b < 2; b++) addj(W_down + (size_t)b * 256 * 64, bt_down[b], 256, 64);
        for (int b = 0; b < 2; b++) addj(W_bil + (size_t)b * 65536, bt_bilT[b], 1024, 64);
        for (int b = 0; b < 2; b++) addj(W_up + (size_t)b * 64 * 256, bt_up[b], 64, 256);
        for (int i = 0; i < 8; i++) addj(W_res_e + (size_t)i * 65536, bt_rese[i], 256, 256);
        for (int b = 0; b < 2; b++) addj(rbf_wh + (size_t)b * 128 * 256, bt_rh[b], 128, 256);
        for (int b = 0; b < 2; b++) addj(W_e2a + (size_t)b * 256 * 128, bt_e2a[b], 256, 128);
        for (int i = 0; i < 4; i++) addj(W_res_a + (size_t)i * 16384, bt_resa[i], 128, 128);
        for (int i = 0; i < 2; i++) addj(W_outF_res + (size_t)i * 65536, bt_Fres[i], 256, 256);
        for (int i = 0; i < 2; i++) addj(W_outE_res + (size_t)i * 16384, bt_Eres[i], 128, 128);
        transpose_weights<<<dim3(384, nj), 256, 0, stream>>>(JB);
    }

    // h0, m0, head slice-0 accumulators
    embed_h<<<(N * 128 + 255) / 256, 256, 0, stream>>>(z, atom_tab, h_cur, N);
    MG2(AM_GATHER, EP_SILU, h_cur, rbf, idx_s, idx_t, bt_edge, m_cur, nbp, E, 384);
    RG(EP_PLAIN, m_cur, bt_outF[0], headF, nbp, E);
    MG(AM_NORMAL, EP_PLAIN, 64, h_cur, nfp, nip, nip, bt_outE[0], headE, nfp, N, 128, 128);

    for (int b = 0; b < NB; ++b) {
        const float* Wcb = W_cbf + (size_t)b * 7 * 16;

        // --- triplet path ---
        MG2(AM_NORMAL, EP_PLAIN, rbf, nfp, nip, nip, bt_r3[b], S1, nbp, E, 128);
        MG(AM_MUL2, EP_PLAIN, 64, m_cur, S1, nip, nip, bt_down[b], xbuf, nbp, E, 64, 256);
        cb16<<<(T * 16 + 255) / 256, 256, 0, stream>>>(cbf, Wcb, cbS, T);
        (void)hipMemsetAsync(agg, 0, (size_t)E * 64 * sizeof(float), stream);
        trip_gemm<<<T / 128, 256, 0, stream>>>(xbuf, cbS, id3_ba, id3_ca, bt_bilT[b], agg);

        // --- residual part 1 ---
        RG(EP_SILU, m_cur, bt_rese[4 * b + 0], S1, nbp, E);
        RG(EP_RES2, S1, bt_rese[4 * b + 1], m_cur, nbp, E);
        // --- inject x3 ---
        MG2(AM_NORMAL, EP_RES2, agg, nfp, nip, nip, bt_up[b], m_cur, nbp, E, 64);
        // --- residual part 2 ---
        RG(EP_SILU, m_cur, bt_rese[4 * b + 2], S1, nbp, E);
        RG(EP_RES2, S1, bt_rese[4 * b + 3], m_cur, nbp, E);
        // --- F-head accumulator ---
        RG(EP_ACCUM, m_cur, bt_outF[b + 1], headF, nbp, E);

        // --- atom update ---
        MG2(AM_NORMAL, EP_PLAIN, rbf, nfp, nip, nip, bt_rh[b], S1, nbp, E, 128);
        MG(AM_MUL2, EP_PLAIN, 128, m_cur, S1, nip, nip, bt_e2a[b], xa, nbp, E, 128, 256);
        (void)hipMemsetAsync(ha, 0, (size_t)N * 128 * sizeof(float), stream);
        scatter_ha<<<(E * 128 + 255) / 256, 256, 0, stream>>>(xa, idx_t, ha, E);
        MG(AM_NORMAL, EP_SILU, 64, ha, nfp, nip, nip, bt_resa[2 * b + 0], tA, nfp, N, 128, 128);
        MG(AM_NORMAL, EP_RESADD, 64, tA, nfp, nip, nip, bt_resa[2 * b + 1], h_cur, ha, N, 128, 128);
        MG(AM_NORMAL, EP_ACCUM, 64, h_cur, nfp, nip, nip, bt_outE[b + 1], headE, nfp, N, 128, 128);
    }

    // --- F head ---
    MG2(AM_SILU, EP_SILU, headF, nbp, nip, nip, bt_Fres[0], S1, nbp, E, 256);
    RG(EP_HEADRES, S1, bt_Fres[1], m_cur, headF, E);
    rowdot<<<(E * 64 + 255) / 256, 256, 0, stream>>>(m_cur, W_outF_fin, Fe, E, 256, 1);

    // --- E head + output ---
    (void)hipMemsetAsync(out, 0, (size_t)out_size * sizeof(float), stream);
    MG(AM_SILU, EP_SILU, 64, headE, nfp, nip, nip, bt_Eres[0], tA, nfp, N, 128, 128);
    MG(AM_NORMAL, EP_HEADRES, 64, tA, nfp, nip, nip, bt_Eres[1], xE, headE, N, 128, 128);
    rowdot<<<(N * 64 + 255) / 256, 256, 0, stream>>>(xE, W_outE_fin, out, N, 128, 4);
    scatter_forces<<<(E + 255) / 256, 256, 0, stream>>>(Fe, V_st, idx_t, out, E);
}

// Round 15
// 2715.651 us; speedup vs baseline: 1.1887x; 1.1887x over previous
//
#include <hip/hip_runtime.h>
#include <hip/hip_bf16.h>
#include <cstdio>

#define INV2 0.70710678118654752440f
typedef __hip_bfloat16 bf16;
typedef __attribute__((ext_vector_type(8))) short short8v;
typedef __attribute__((ext_vector_type(8))) unsigned short u16x8;
typedef __attribute__((ext_vector_type(4))) float f32x4;

__device__ __forceinline__ float silu_f(float v) { return v / (1.0f + __expf(-v)); }
__device__ __forceinline__ float bf2f(unsigned short u) {
    union { unsigned int i; float f; } t; t.i = ((unsigned int)u) << 16; return t.f;
}
__device__ __forceinline__ unsigned short f2bf(float x) {
    bf16 b = __float2bfloat16(x);
    return *reinterpret_cast<unsigned short*>(&b);
}
__device__ __forceinline__ float toF(float v) { return v; }
__device__ __forceinline__ float toF(bf16 v) { return __bfloat162float(v); }
__device__ __forceinline__ void stF(float* p, float v) { *p = v; }
__device__ __forceinline__ void stF(bf16* p, float v) { *p = __float2bfloat16(v); }

__device__ __forceinline__ void ld8f(const float* p, float* o) {
    const float4 a = ((const float4*)p)[0], b = ((const float4*)p)[1];
    o[0]=a.x; o[1]=a.y; o[2]=a.z; o[3]=a.w; o[4]=b.x; o[5]=b.y; o[6]=b.z; o[7]=b.w;
}
__device__ __forceinline__ void ld8f(const bf16* p, float* o) {
    const u16x8 u = *(const u16x8*)p;
#pragma unroll
    for (int j = 0; j < 8; j++) o[j] = bf2f(u[j]);
}

// async global->LDS, 16B per lane
__device__ __forceinline__ void gll16(const void* g, void* l) {
    __builtin_amdgcn_global_load_lds(
        (const __attribute__((address_space(1))) unsigned int*)g,
        (__attribute__((address_space(3))) unsigned int*)l, 16, 0, 0);
}

enum { AM_NORMAL = 0, AM_MUL2 = 1, AM_GATHER = 2, AM_SILU = 3, AM_DMA = 4 };
enum { EP_PLAIN = 0, EP_SILU = 1, EP_ACCUM = 2, EP_RES2 = 3, EP_RESADD = 4, EP_HEADRES = 5 };

__device__ __forceinline__ float epi_val(int EPI, float v, float c, float x) {
    if (EPI == EP_PLAIN)   return v;
    if (EPI == EP_SILU)    return silu_f(v);
    if (EPI == EP_ACCUM)   return c + v;
    if (EPI == EP_RES2)    return (c + silu_f(v)) * INV2;
    if (EPI == EP_RESADD)  return c + (x + silu_f(v)) * INV2;
    /* EP_HEADRES */       return (silu_f(x) + silu_f(v)) * INV2;
}

// ---------------- R7 mgemm (256 threads) for N<=128 outputs ----------------
template <int AMODE, int EPI, int BN, typename AT, typename CT>
__global__ __launch_bounds__(256) void mgemm(
    const AT* __restrict__ A, const AT* __restrict__ A2,
    const int* __restrict__ gs, const int* __restrict__ gt,
    const bf16* __restrict__ Bt,
    CT* __restrict__ C, const CT* __restrict__ X,
    int Mrows, int Ncols, int K)
{
    constexpr bool DMA = (AMODE == AM_DMA);
    constexpr int AST = DMA ? 32 : 40;
    constexpr int FM = (BN == 128) ? 4 : 2;
    __shared__ __align__(16) unsigned short Als[128 * AST];
    __shared__ __align__(16) unsigned short Bls[BN * 32];
    const int tid = threadIdx.x;
    const int row0 = blockIdx.x * 128, col0 = blockIdx.y * BN;

    const int sr = tid >> 1;
    const int sh = (tid & 1) * 16;
    const int gr = row0 + sr;
    const bool rok = (gr < Mrows);
    int is_ = 0, it_ = 0;
    if (AMODE == AM_GATHER) { if (rok) { is_ = gs[gr]; it_ = gt[gr]; } }

    const int l = tid & 63, wid = tid >> 6;
    const int lr = l & 15;
    const int lk = (l >> 4) * 8;
    const int wrow = (BN == 128) ? ((wid & 1) * 64) : (wid * 32);
    const int wcol = (BN == 128) ? ((wid >> 1) * 64) : 0;

    f32x4 acc[FM][4];
#pragma unroll
    for (int i = 0; i < FM; i++)
#pragma unroll
        for (int j = 0; j < 4; j++)
#pragma unroll
            for (int q = 0; q < 4; q++) acc[i][j][q] = 0.f;

    for (int k0 = 0; k0 < K; k0 += 32) {
        if constexpr (DMA) {
#pragma unroll
            for (int i = 0; i < 2; i++) {
                const int c = i * 256 + tid;
                const int row = c >> 2;
                if (row0 + row < Mrows)
                    gll16(A + (size_t)(row0 + row) * K + k0 + (c & 3) * 8, &Als[c * 8]);
            }
        } else {
            float va[16];
            if (rok) {
                if (AMODE == AM_GATHER) {
                    const int reg = k0 >> 7, koff = (k0 & 127) + sh;
                    const AT* src = (reg == 0) ? (A + (size_t)is_ * 128 + koff)
                                  : (reg == 1) ? (A + (size_t)it_ * 128 + koff)
                                               : (A2 + (size_t)gr * 128 + koff);
                    ld8f(src, va); ld8f(src + 8, va + 8);
                } else {
                    const AT* src = A + (size_t)gr * K + k0 + sh;
                    ld8f(src, va); ld8f(src + 8, va + 8);
                    if (AMODE == AM_MUL2) {
                        float vb[16];
                        const AT* s2 = A2 + (size_t)gr * K + k0 + sh;
                        ld8f(s2, vb); ld8f(s2 + 8, vb + 8);
#pragma unroll
                        for (int j = 0; j < 16; j++) va[j] *= vb[j];
                    } else if (AMODE == AM_SILU) {
#pragma unroll
                        for (int j = 0; j < 16; j++) va[j] = silu_f(va[j]);
                    }
                }
            } else {
#pragma unroll
                for (int j = 0; j < 16; j++) va[j] = 0.f;
            }
            u16x8 av0, av1;
#pragma unroll
            for (int j = 0; j < 8; j++) { av0[j] = f2bf(va[j]); av1[j] = f2bf(va[j + 8]); }
            *(u16x8*)&Als[sr * AST + sh] = av0;
            *(u16x8*)&Als[sr * AST + sh + 8] = av1;
        }

#pragma unroll
        for (int i = 0; i < BN / 64; i++) {
            const int c = i * 256 + tid;
            gll16(Bt + (size_t)(col0 + (c >> 2)) * K + k0 + (c & 3) * 8, &Bls[c * 8]);
        }

        __syncthreads();

        short8v af[FM], bfr[4];
#pragma unroll
        for (int fm = 0; fm < FM; fm++)
            af[fm] = *(const short8v*)&Als[(wrow + fm * 16 + lr) * AST + lk];
#pragma unroll
        for (int fn = 0; fn < 4; fn++)
            bfr[fn] = *(const short8v*)&Bls[(wcol + fn * 16 + lr) * 32 + lk];
#pragma unroll
        for (int fm = 0; fm < FM; fm++)
#pragma unroll
            for (int fn = 0; fn < 4; fn++)
                acc[fm][fn] = __builtin_amdgcn_mfma_f32_16x16x32_bf16(
                    af[fm], bfr[fn], acc[fm][fn], 0, 0, 0);

        __syncthreads();
    }

#pragma unroll
    for (int fm = 0; fm < FM; fm++) {
        const int rb = row0 + wrow + fm * 16 + (l >> 4) * 4;
#pragma unroll
        for (int fn = 0; fn < 4; fn++) {
            const int c = col0 + wcol + fn * 16 + lr;
#pragma unroll
            for (int r = 0; r < 4; r++) {
                const int rr = rb + r;
                if (rr >= Mrows) continue;
                const size_t o = (size_t)rr * Ncols + c;
                stF(&C[o], epi_val(EPI, acc[fm][fn][r],
                                   (EPI >= EP_ACCUM) ? toF(C[o]) : 0.f,
                                   (EPI == EP_RESADD || EPI == EP_HEADRES) ? toF(X[o]) : 0.f));
            }
        }
    }
}

// ---------------- wide mgemm2: BM=128 x BN=256, 512 threads, PERSISTENT ----------------
// Grid-strided over row-tiles: few long-lived blocks instead of one block per
// tile (tests/kills the workgroup-launch-rate limit seen across R8-R14).
template <int AMODE, int EPI, typename AT, typename CT>
__global__ __launch_bounds__(512) void mgemm2(
    const AT* __restrict__ A, const AT* __restrict__ A2,
    const int* __restrict__ gs, const int* __restrict__ gt,
    const bf16* __restrict__ Bt,
    CT* __restrict__ C, const CT* __restrict__ X,
    int Mrows, int K)
{
    constexpr bool DMA = (AMODE == AM_DMA);
    constexpr int AST = DMA ? 32 : 40;
    __shared__ __align__(16) unsigned short Als[2][128 * AST];
    __shared__ __align__(16) unsigned short Bls[2][256 * 32];
    const int tid = threadIdx.x;

    const int l = tid & 63, wid = tid >> 6;
    const int lr = l & 15;
    const int lk = (l >> 4) * 8;
    const int wrow = (wid & 1) * 64;
    const int wcol = (wid >> 1) * 64;

    const int ntiles = (Mrows + 127) >> 7;

    for (int t = blockIdx.x; t < ntiles; t += gridDim.x) {
        const int row0 = t * 128;
        const int sr = tid >> 2;
        const int sh = (tid & 3) * 8;
        const int gr = row0 + sr;
        const bool rok = (gr < Mrows);
        int is_ = 0, it_ = 0;
        if (AMODE == AM_GATHER) { if (rok) { is_ = gs[gr]; it_ = gt[gr]; } }

        f32x4 acc[4][4];
#pragma unroll
        for (int i = 0; i < 4; i++)
#pragma unroll
            for (int j = 0; j < 4; j++)
#pragma unroll
                for (int q = 0; q < 4; q++) acc[i][j][q] = 0.f;

        for (int k0 = 0; k0 < K; k0 += 64) {
            float va0[8], va1[8];
#pragma unroll
            for (int h = 0; h < 2; h++) {
                const int kk = k0 + h * 32;
                if constexpr (DMA) {
                    const int row = tid >> 2;
                    if (row0 + row < Mrows)
                        gll16(A + (size_t)(row0 + row) * K + kk + (tid & 3) * 8, &Als[h][tid * 8]);
                } else {
                    float* va = h ? va1 : va0;
                    if (rok) {
                        if (AMODE == AM_GATHER) {
                            const int reg = kk >> 7, koff = (kk & 127) + sh;
                            const AT* src = (reg == 0) ? (A + (size_t)is_ * 128 + koff)
                                          : (reg == 1) ? (A + (size_t)it_ * 128 + koff)
                                                       : (A2 + (size_t)gr * 128 + koff);
                            ld8f(src, va);
                        } else {
                            ld8f(A + (size_t)gr * K + kk + sh, va);
                            if (AMODE == AM_MUL2) {
                                float vb[8];
                                ld8f(A2 + (size_t)gr * K + kk + sh, vb);
#pragma unroll
                                for (int j = 0; j < 8; j++) va[j] *= vb[j];
                            } else if (AMODE == AM_SILU) {
#pragma unroll
                                for (int j = 0; j < 8; j++) va[j] = silu_f(va[j]);
                            }
                        }
                    } else {
#pragma unroll
                        for (int j = 0; j < 8; j++) va[j] = 0.f;
                    }
                }
#pragma unroll
                for (int i = 0; i < 2; i++) {
                    const int c = i * 512 + tid;
                    gll16(Bt + (size_t)(c >> 2) * K + kk + (c & 3) * 8, &Bls[h][c * 8]);
                }
            }
            if constexpr (!DMA) {
                u16x8 av0, av1;
#pragma unroll
                for (int j = 0; j < 8; j++) { av0[j] = f2bf(va0[j]); av1[j] = f2bf(va1[j]); }
                *(u16x8*)&Als[0][sr * AST + sh] = av0;
                *(u16x8*)&Als[1][sr * AST + sh] = av1;
            }

            __syncthreads();

#pragma unroll
            for (int h = 0; h < 2; h++) {
                short8v af[4], bfr[4];
#pragma unroll
                for (int fm = 0; fm < 4; fm++)
                    af[fm] = *(const short8v*)&Als[h][(wrow + fm * 16 + lr) * AST + lk];
#pragma unroll
                for (int fn = 0; fn < 4; fn++)
                    bfr[fn] = *(const short8v*)&Bls[h][(wcol + fn * 16 + lr) * 32 + lk];
#pragma unroll
                for (int fm = 0; fm < 4; fm++)
#pragma unroll
                    for (int fn = 0; fn < 4; fn++)
                        acc[fm][fn] = __builtin_amdgcn_mfma_f32_16x16x32_bf16(
                            af[fm], bfr[fn], acc[fm][fn], 0, 0, 0);
            }

            __syncthreads();
        }

#pragma unroll
        for (int fm = 0; fm < 4; fm++) {
            const int rb = row0 + wrow + fm * 16 + (l >> 4) * 4;
#pragma unroll
            for (int fn = 0; fn < 4; fn++) {
                const int c = wcol + fn * 16 + lr;
#pragma unroll
                for (int r = 0; r < 4; r++) {
                    const int rr = rb + r;
                    if (rr >= Mrows) continue;
                    const size_t o = (size_t)rr * 256 + c;
                    stF(&C[o], epi_val(EPI, acc[fm][fn][r],
                                       (EPI >= EP_ACCUM) ? toF(C[o]) : 0.f,
                                       (EPI == EP_RESADD || EPI == EP_HEADRES) ? toF(X[o]) : 0.f));
                }
            }
        }
        // trailing K-loop barrier already ensured LDS reads done; epilogue
        // touches no LDS, so next tile's staging is safe.
    }
}

// ---------------- fused triplet GEMM ----------------
__global__ __launch_bounds__(256) void trip_gemm(
    const bf16* __restrict__ x,     // [E,64]
    const bf16* __restrict__ cb,    // [T,16]
    const int* __restrict__ ba, const int* __restrict__ ca,
    const bf16* __restrict__ BtT,   // [64][1024]
    float* __restrict__ agg)
{
    __shared__ __align__(16) unsigned short At[128 * 40];
    __shared__ __align__(16) unsigned short Bs[64 * 40];
    const int tid = threadIdx.x;
    const int gr0 = blockIdx.x * 128;

    const int sr = tid >> 1, sh = tid & 1;
    const int gr = gr0 + sr;
    const int e = ba[gr];
    float xr[32];
    {
        const bf16* xp = x + (size_t)e * 64 + sh * 16;
        const u16x8 a0 = *(const u16x8*)xp;
        const u16x8 a1 = *(const u16x8*)(xp + 8);
        const u16x8 b0 = *(const u16x8*)(xp + 32);
        const u16x8 b1 = *(const u16x8*)(xp + 40);
#pragma unroll
        for (int j = 0; j < 8; j++) {
            xr[j] = bf2f(a0[j]); xr[8 + j] = bf2f(a1[j]);
            xr[16 + j] = bf2f(b0[j]); xr[24 + j] = bf2f(b1[j]);
        }
    }
    float cbr[16];
    {
        const u16x8 c0 = *(const u16x8*)(cb + (size_t)gr * 16);
        const u16x8 c1 = *(const u16x8*)(cb + (size_t)gr * 16 + 8);
#pragma unroll
        for (int j = 0; j < 8; j++) { cbr[j] = bf2f(c0[j]); cbr[8 + j] = bf2f(c1[j]); }
    }

    const int l = tid & 63, wv = tid >> 6;
    const int lr = l & 15, lg = l >> 4, lk = lg * 8;
    const int wrow = wv * 32;
    const int bcol = tid >> 2, bq = tid & 3;

    f32x4 acc[2][4];
#pragma unroll
    for (int i = 0; i < 2; i++)
#pragma unroll
        for (int j = 0; j < 4; j++)
#pragma unroll
            for (int q = 0; q < 4; q++) acc[i][j][q] = 0.f;

#pragma unroll 4
    for (int ks = 0; ks < 32; ++ks) {
        const float cbv = cbr[ks >> 1];
        const int ib = (ks & 1) * 16;
        u16x8 p0, p1;
#pragma unroll
        for (int j = 0; j < 8; j++) {
            p0[j] = f2bf(cbv * xr[ib + j]);
            p1[j] = f2bf(cbv * xr[ib + 8 + j]);
        }
        *(u16x8*)&At[sr * 40 + sh * 16] = p0;
        *(u16x8*)&At[sr * 40 + sh * 16 + 8] = p1;
        const u16x8 bv8 = *(const u16x8*)(BtT + (size_t)bcol * 1024 + ks * 32 + bq * 8);
        *(u16x8*)&Bs[bcol * 40 + bq * 8] = bv8;
        __syncthreads();

        short8v af[2], bf4[4];
        af[0] = *(const short8v*)&At[(wrow + lr) * 40 + lk];
        af[1] = *(const short8v*)&At[(wrow + 16 + lr) * 40 + lk];
#pragma unroll
        for (int fn = 0; fn < 4; fn++)
            bf4[fn] = *(const short8v*)&Bs[(fn * 16 + lr) * 40 + lk];
#pragma unroll
        for (int fm = 0; fm < 2; fm++)
#pragma unroll
            for (int fn = 0; fn < 4; fn++)
                acc[fm][fn] = __builtin_amdgcn_mfma_f32_16x16x32_bf16(
                    af[fm], bf4[fn], acc[fm][fn], 0, 0, 0);
        __syncthreads();
    }

#pragma unroll
    for (int fm = 0; fm < 2; fm++)
#pragma unroll
        for (int q = 0; q < 4; q++) {
            const int rr = wrow + fm * 16 + lg * 4 + q;
            const int eo = ca[gr0 + rr];
#pragma unroll
            for (int fn = 0; fn < 4; fn++)
                atomicAdd(&agg[(size_t)eo * 64 + fn * 16 + lr], acc[fm][fn][q]);
        }
}

__global__ __launch_bounds__(256) void cb16(const float* __restrict__ cbf,
                                            const float* __restrict__ Wcb,
                                            bf16* __restrict__ cb, int T)
{
    const int gid = blockIdx.x * 256 + threadIdx.x;
    const int t = gid >> 4, c = gid & 15;
    if (t >= T) return;
    const float* cr = cbf + (size_t)t * 7;
    float s = 0.f;
#pragma unroll
    for (int k = 0; k < 7; k++) s += cr[k] * Wcb[k * 16 + c];
    cb[(size_t)t * 16 + c] = __float2bfloat16(s);
}

struct TJob { const float* src; bf16* dst; int K; int N; };
struct TJobs { TJob j[40]; };

__global__ __launch_bounds__(256) void transpose_weights(TJobs JB) {
    const TJob J = JB.j[blockIdx.y];
    const int total = J.K * J.N;
    const int gid = blockIdx.x * 256 + threadIdx.x;
    if (gid >= total) return;
    const int n = gid / J.K, k = gid - n * J.K;
    J.dst[(size_t)n * J.K + k] = __float2bfloat16(J.src[(size_t)k * J.N + n]);
}

__global__ __launch_bounds__(256) void embed_h(const int* __restrict__ z,
                                               const float* __restrict__ tab,
                                               float* __restrict__ h, int N)
{
    const int gid = blockIdx.x * 256 + threadIdx.x;
    const int n = gid >> 7, j = gid & 127;
    if (n >= N) return;
    h[(size_t)n * 128 + j] = tab[(size_t)z[n] * 128 + j];
}

__global__ __launch_bounds__(256) void scatter_ha(const bf16* __restrict__ xa,
                                                  const int* __restrict__ idxt,
                                                  float* __restrict__ ha, int E)
{
    const int gid = blockIdx.x * 256 + threadIdx.x;
    const int e = gid >> 7, j = gid & 127;
    if (e >= E) return;
    atomicAdd(&ha[(size_t)idxt[e] * 128 + j], toF(xa[(size_t)e * 128 + j]));
}

template <typename AT>
__global__ __launch_bounds__(256) void rowdot(const AT* __restrict__ Xm,
                                              const float* __restrict__ w,
                                              float* __restrict__ outv,
                                              int rows, int width, int ostride)
{
    const int wid = (blockIdx.x * 256 + threadIdx.x) >> 6;
    const int lane = threadIdx.x & 63;
    if (wid >= rows) return;
    float s = 0.f;
    for (int q = lane; q < width; q += 64) s += toF(Xm[(size_t)wid * width + q]) * w[q];
#pragma unroll
    for (int off = 32; off > 0; off >>= 1) s += __shfl_down(s, off);
    if (lane == 0) outv[(size_t)wid * ostride] = s;
}

__global__ __launch_bounds__(256) void scatter_forces(const float* __restrict__ Fe,
                                                      const float* __restrict__ Vst,
                                                      const int* __restrict__ idxt,
                                                      float* __restrict__ out, int E)
{
    const int e = blockIdx.x * 256 + threadIdx.x;
    if (e >= E) return;
    const float f = Fe[e];
    const int n = idxt[e];
    atomicAdd(&out[(size_t)n * 4 + 1], f * Vst[(size_t)e * 3 + 0]);
    atomicAdd(&out[(size_t)n * 4 + 2], f * Vst[(size_t)e * 3 + 1]);
    atomicAdd(&out[(size_t)n * 4 + 3], f * Vst[(size_t)e * 3 + 2]);
}

#define MG(AM, EP, BNv, Aptr, A2p, GS, GT, Btp, Cp, Xp, MR, NC, KK)                       \
    mgemm<AM, EP, BNv><<<dim3(((MR) + 127) / 128, (NC) / (BNv)), 256, 0, stream>>>(       \
        Aptr, A2p, GS, GT, Btp, Cp, Xp, MR, NC, KK)

#define MG2(AM, EP, Aptr, A2p, GS, GT, Btp, Cp, Xp, MR, KK)                               \
    mgemm2<AM, EP><<<(((MR) + 127) / 128 < 1024 ? ((MR) + 127) / 128 : 1024),             \
                    512, 0, stream>>>(Aptr, A2p, GS, GT, Btp, Cp, Xp, MR, KK)

extern "C" void kernel_launch(void* const* d_in, const int* in_sizes, int n_in,
                              void* d_out, int out_size, void* d_ws, size_t ws_size,
                              hipStream_t stream)
{
    const int N = in_sizes[0];
    const int E = in_sizes[1];
    const int T = in_sizes[3];
    const int NB = 2;

    const int*   z        = (const int*)d_in[0];
    const int*   idx_s    = (const int*)d_in[1];
    const int*   idx_t    = (const int*)d_in[2];
    const int*   id3_ba   = (const int*)d_in[3];
    const int*   id3_ca   = (const int*)d_in[4];
    const float* rbf      = (const float*)d_in[5];
    const float* cbf      = (const float*)d_in[6];
    const float* V_st     = (const float*)d_in[7];
    const float* atom_tab = (const float*)d_in[8];
    const float* W_edge_in= (const float*)d_in[9];
    const float* rbf_w3   = (const float*)d_in[10];
    const float* W_down   = (const float*)d_in[11];
    const float* W_cbf    = (const float*)d_in[12];
    const float* W_bil    = (const float*)d_in[13];
    const float* W_up     = (const float*)d_in[14];
    const float* W_res_e  = (const float*)d_in[15];
    const float* rbf_wh   = (const float*)d_in[16];
    const float* W_e2a    = (const float*)d_in[17];
    const float* W_res_a  = (const float*)d_in[18];
    const float* W_outE_in  = (const float*)d_in[19];
    const float* W_outE_res = (const float*)d_in[20];
    const float* W_outE_fin = (const float*)d_in[21];
    const float* W_outF_in  = (const float*)d_in[22];
    const float* W_outF_res = (const float*)d_in[23];
    const float* W_outF_fin = (const float*)d_in[24];

    float* out = (float*)d_out;

    // ---- workspace layout ----
    char* base = (char*)d_ws;
    size_t off = 0;
    auto alloc = [&](size_t nbytes) { char* p = base + off; off += (nbytes + 15) & ~(size_t)15; return p; };
    bf16*  m_cur = (bf16*)alloc((size_t)E * 256 * 2);
    bf16*  headF = (bf16*)alloc((size_t)E * 256 * 2);
    bf16*  S1    = (bf16*)alloc((size_t)E * 256 * 2);
    float* agg   = (float*)alloc((size_t)E * 64 * 4);
    bf16*  xbuf  = (bf16*)alloc((size_t)E * 64 * 2);
    float* h_cur = (float*)alloc((size_t)N * 128 * 4);
    float* headE = (float*)alloc((size_t)N * 128 * 4);
    float* ha    = (float*)alloc((size_t)N * 128 * 4);
    float* tA    = (float*)alloc((size_t)N * 128 * 4);
    bf16 *bt_outF[3], *bt_outE[3], *bt_r3[2], *bt_down[2], *bt_bilT[2], *bt_up[2],
         *bt_rese[8], *bt_rh[2], *bt_e2a[2], *bt_resa[4], *bt_Fres[2], *bt_Eres[2];
    bf16* bt_edge = (bf16*)alloc(384 * 256 * 2);
    for (int s = 0; s < 3; s++) bt_outF[s] = (bf16*)alloc(256 * 256 * 2);
    for (int s = 0; s < 3; s++) bt_outE[s] = (bf16*)alloc(128 * 128 * 2);
    for (int b = 0; b < 2; b++) bt_r3[b]   = (bf16*)alloc(256 * 128 * 2);
    for (int b = 0; b < 2; b++) bt_down[b] = (bf16*)alloc(64 * 256 * 2);
    for (int b = 0; b < 2; b++) bt_bilT[b] = (bf16*)alloc(64 * 1024 * 2);
    for (int b = 0; b < 2; b++) bt_up[b]   = (bf16*)alloc(256 * 64 * 2);
    for (int i = 0; i < 8; i++) bt_rese[i] = (bf16*)alloc(256 * 256 * 2);
    for (int b = 0; b < 2; b++) bt_rh[b]   = (bf16*)alloc(256 * 128 * 2);
    for (int b = 0; b < 2; b++) bt_e2a[b]  = (bf16*)alloc(128 * 256 * 2);
    for (int i = 0; i < 4; i++) bt_resa[i] = (bf16*)alloc(128 * 128 * 2);
    for (int i = 0; i < 2; i++) bt_Fres[i] = (bf16*)alloc(256 * 256 * 2);
    for (int i = 0; i < 2; i++) bt_Eres[i] = (bf16*)alloc(128 * 128 * 2);
    if (off > ws_size) {
        fprintf(stderr, "kernel_launch: ws too small: need %zu have %zu\n", off, ws_size);
        return;
    }
    bf16*  xa = (bf16*)agg;    // [E,128] bf16, agg region reused post-triplet
    float* Fe = (float*)xbuf;  // [E] f32 post-loop
    float* xE = ha;            // [N,128] f32 post-loop
    bf16*  cbS = S1;           // [T,16] bf16 during triplet

    const float* nfp = nullptr;
    const bf16*  nbp = nullptr;
    const int*   nip = nullptr;

    // ---- weight transposes ----
    {
        TJobs JB; int nj = 0;
        auto addj = [&](const float* s, bf16* d, int K, int Nn) { JB.j[nj++] = TJob{s, d, K, Nn}; };
        addj(W_edge_in, bt_edge, 384, 256);
        for (int s = 0; s < 3; s++) addj(W_outF_in + (size_t)s * 256 * 256, bt_outF[s], 256, 256);
        for (int s = 0; s < 3; s++) addj(W_outE_in + (size_t)s * 128 * 128, bt_outE[s], 128, 128);
        for (int b = 0; b < 2; b++) addj(rbf_w3 + (size_t)b * 128 * 256, bt_r3[b], 128, 256);
        for (int b = 0; b < 2; b++) addj(W_down + (size_t)b * 256 * 64, bt_down[b], 256, 64);
        for (int b = 0; b < 2; b++) addj(W_bil + (size_t)b * 65536, bt_bilT[b], 1024, 64);
        for (int b = 0; b < 2; b++) addj(W_up + (size_t)b * 64 * 256, bt_up[b], 64, 256);
        for (int i = 0; i < 8; i++) addj(W_res_e + (size_t)i * 65536, bt_rese[i], 256, 256);
        for (int b = 0; b < 2; b++) addj(rbf_wh + (size_t)b * 128 * 256, bt_rh[b], 128, 256);
        for (int b = 0; b < 2; b++) addj(W_e2a + (size_t)b * 256 * 128, bt_e2a[b], 256, 128);
        for (int i = 0; i < 4; i++) addj(W_res_a + (size_t)i * 16384, bt_resa[i], 128, 128);
        for (int i = 0; i < 2; i++) addj(W_outF_res + (size_t)i * 65536, bt_Fres[i], 256, 256);
        for (int i = 0; i < 2; i++) addj(W_outE_res + (size_t)i * 16384, bt_Eres[i], 128, 128);
        transpose_weights<<<dim3(384, nj), 256, 0, stream>>>(JB);
    }

    // h0, m0, head slice-0 accumulators
    embed_h<<<(N * 128 + 255) / 256, 256, 0, stream>>>(z, atom_tab, h_cur, N);
    MG2(AM_GATHER, EP_SILU, h_cur, rbf, idx_s, idx_t, bt_edge, m_cur, nbp, E, 384);
    MG2(AM_DMA, EP_PLAIN, m_cur, nbp, nip, nip, bt_outF[0], headF, nbp, E, 256);
    MG(AM_NORMAL, EP_PLAIN, 64, h_cur, nfp, nip, nip, bt_outE[0], headE, nfp, N, 128, 128);

    for (int b = 0; b < NB; ++b) {
        const float* Wcb = W_cbf + (size_t)b * 7 * 16;

        // --- triplet path ---
        MG2(AM_NORMAL, EP_PLAIN, rbf, nfp, nip, nip, bt_r3[b], S1, nbp, E, 128);
        MG(AM_MUL2, EP_PLAIN, 64, m_cur, S1, nip, nip, bt_down[b], xbuf, nbp, E, 64, 256);
        cb16<<<(T * 16 + 255) / 256, 256, 0, stream>>>(cbf, Wcb, cbS, T);
        (void)hipMemsetAsync(agg, 0, (size_t)E * 64 * sizeof(float), stream);
        trip_gemm<<<T / 128, 256, 0, stream>>>(xbuf, cbS, id3_ba, id3_ca, bt_bilT[b], agg);

        // --- residual part 1 ---
        MG2(AM_DMA, EP_SILU, m_cur, nbp, nip, nip, bt_rese[4 * b + 0], S1, nbp, E, 256);
        MG2(AM_DMA, EP_RES2, S1, nbp, nip, nip, bt_rese[4 * b + 1], m_cur, nbp, E, 256);
        // --- inject x3 ---
        MG2(AM_NORMAL, EP_RES2, agg, nfp, nip, nip, bt_up[b], m_cur, nbp, E, 64);
        // --- residual part 2 ---
        MG2(AM_DMA, EP_SILU, m_cur, nbp, nip, nip, bt_rese[4 * b + 2], S1, nbp, E, 256);
        MG2(AM_DMA, EP_RES2, S1, nbp, nip, nip, bt_rese[4 * b + 3], m_cur, nbp, E, 256);
        // --- F-head accumulator ---
        MG2(AM_DMA, EP_ACCUM, m_cur, nbp, nip, nip, bt_outF[b + 1], headF, nbp, E, 256);

        // --- atom update ---
        MG2(AM_NORMAL, EP_PLAIN, rbf, nfp, nip, nip, bt_rh[b], S1, nbp, E, 128);
        MG(AM_MUL2, EP_PLAIN, 128, m_cur, S1, nip, nip, bt_e2a[b], xa, nbp, E, 128, 256);
        (void)hipMemsetAsync(ha, 0, (size_t)N * 128 * sizeof(float), stream);
        scatter_ha<<<(E * 128 + 255) / 256, 256, 0, stream>>>(xa, idx_t, ha, E);
        MG(AM_NORMAL, EP_SILU, 64, ha, nfp, nip, nip, bt_resa[2 * b + 0], tA, nfp, N, 128, 128);
        MG(AM_NORMAL, EP_RESADD, 64, tA, nfp, nip, nip, bt_resa[2 * b + 1], h_cur, ha, N, 128, 128);
        MG(AM_NORMAL, EP_ACCUM, 64, h_cur, nfp, nip, nip, bt_outE[b + 1], headE, nfp, N, 128, 128);
    }

    // --- F head ---
    MG2(AM_SILU, EP_SILU, headF, nbp, nip, nip, bt_Fres[0], S1, nbp, E, 256);
    MG2(AM_DMA, EP_HEADRES, S1, nbp, nip, nip, bt_Fres[1], m_cur, headF, E, 256);
    rowdot<<<(E * 64 + 255) / 256, 256, 0, stream>>>(m_cur, W_outF_fin, Fe, E, 256, 1);

    // --- E head + output ---
    (void)hipMemsetAsync(out, 0, (size_t)out_size * sizeof(float), stream);
    MG(AM_SILU, EP_SILU, 64, headE, nfp, nip, nip, bt_Eres[0], tA, nfp, N, 128, 128);
    MG(AM_NORMAL, EP_HEADRES, 64, tA, nfp, nip, nip, bt_Eres[1], xE, headE, N, 128, 128);
    rowdot<<<(N * 64 + 255) / 256, 256, 0, stream>>>(xE, W_outE_fin, out, N, 128, 4);
    scatter_forces<<<(E + 255) / 256, 256, 0, stream>>>(Fe, V_st, idx_t, out, E);
}

// Round 16
// 2419.746 us; speedup vs baseline: 1.3340x; 1.1223x over previous
//
#include <hip/hip_runtime.h>
#include <hip/hip_bf16.h>
#include <cstdio>

#define INV2 0.70710678118654752440f
typedef __hip_bfloat16 bf16;
typedef __attribute__((ext_vector_type(8))) short short8v;
typedef __attribute__((ext_vector_type(8))) unsigned short u16x8;
typedef __attribute__((ext_vector_type(4))) float f32x4;

__device__ __forceinline__ float silu_f(float v) { return v / (1.0f + __expf(-v)); }
__device__ __forceinline__ float bf2f(unsigned short u) {
    union { unsigned int i; float f; } t; t.i = ((unsigned int)u) << 16; return t.f;
}
__device__ __forceinline__ unsigned short f2bf(float x) {
    bf16 b = __float2bfloat16(x);
    return *reinterpret_cast<unsigned short*>(&b);
}
__device__ __forceinline__ float toF(float v) { return v; }
__device__ __forceinline__ float toF(bf16 v) { return __bfloat162float(v); }
__device__ __forceinline__ void stF(float* p, float v) { *p = v; }
__device__ __forceinline__ void stF(bf16* p, float v) { *p = __float2bfloat16(v); }

__device__ __forceinline__ void ld8f(const float* p, float* o) {
    const float4 a = ((const float4*)p)[0], b = ((const float4*)p)[1];
    o[0]=a.x; o[1]=a.y; o[2]=a.z; o[3]=a.w; o[4]=b.x; o[5]=b.y; o[6]=b.z; o[7]=b.w;
}
__device__ __forceinline__ void ld8f(const bf16* p, float* o) {
    const u16x8 u = *(const u16x8*)p;
#pragma unroll
    for (int j = 0; j < 8; j++) o[j] = bf2f(u[j]);
}

// async global->LDS, 16B per lane
__device__ __forceinline__ void gll16(const void* g, void* l) {
    __builtin_amdgcn_global_load_lds(
        (const __attribute__((address_space(1))) unsigned int*)g,
        (__attribute__((address_space(3))) unsigned int*)l, 16, 0, 0);
}

enum { AM_NORMAL = 0, AM_MUL2 = 1, AM_GATHER = 2, AM_SILU = 3, AM_DMA = 4 };
enum { EP_PLAIN = 0, EP_SILU = 1, EP_ACCUM = 2, EP_RES2 = 3, EP_RESADD = 4, EP_HEADRES = 5 };

__device__ __forceinline__ float epi_val(int EPI, float v, float c, float x) {
    if (EPI == EP_PLAIN)   return v;
    if (EPI == EP_SILU)    return silu_f(v);
    if (EPI == EP_ACCUM)   return c + v;
    if (EPI == EP_RES2)    return (c + silu_f(v)) * INV2;
    if (EPI == EP_RESADD)  return c + (x + silu_f(v)) * INV2;
    /* EP_HEADRES */       return (silu_f(x) + silu_f(v)) * INV2;
}

// ---------------- R7 mgemm (256 threads) for N<=128 outputs ----------------
template <int AMODE, int EPI, int BN, typename AT, typename CT>
__global__ __launch_bounds__(256) void mgemm(
    const AT* __restrict__ A, const AT* __restrict__ A2,
    const int* __restrict__ gs, const int* __restrict__ gt,
    const bf16* __restrict__ Bt,
    CT* __restrict__ C, const CT* __restrict__ X,
    int Mrows, int Ncols, int K)
{
    constexpr bool DMA = (AMODE == AM_DMA);
    constexpr int AST = DMA ? 32 : 40;
    constexpr int FM = (BN == 128) ? 4 : 2;
    __shared__ __align__(16) unsigned short Als[128 * AST];
    __shared__ __align__(16) unsigned short Bls[BN * 32];
    const int tid = threadIdx.x;
    const int row0 = blockIdx.x * 128, col0 = blockIdx.y * BN;

    const int sr = tid >> 1;
    const int sh = (tid & 1) * 16;
    const int gr = row0 + sr;
    const bool rok = (gr < Mrows);
    int is_ = 0, it_ = 0;
    if (AMODE == AM_GATHER) { if (rok) { is_ = gs[gr]; it_ = gt[gr]; } }

    const int l = tid & 63, wid = tid >> 6;
    const int lr = l & 15;
    const int lk = (l >> 4) * 8;
    const int wrow = (BN == 128) ? ((wid & 1) * 64) : (wid * 32);
    const int wcol = (BN == 128) ? ((wid >> 1) * 64) : 0;

    f32x4 acc[FM][4];
#pragma unroll
    for (int i = 0; i < FM; i++)
#pragma unroll
        for (int j = 0; j < 4; j++)
#pragma unroll
            for (int q = 0; q < 4; q++) acc[i][j][q] = 0.f;

    for (int k0 = 0; k0 < K; k0 += 32) {
        if constexpr (DMA) {
#pragma unroll
            for (int i = 0; i < 2; i++) {
                const int c = i * 256 + tid;
                const int row = c >> 2;
                if (row0 + row < Mrows)
                    gll16(A + (size_t)(row0 + row) * K + k0 + (c & 3) * 8, &Als[c * 8]);
            }
        } else {
            float va[16];
            if (rok) {
                if (AMODE == AM_GATHER) {
                    const int reg = k0 >> 7, koff = (k0 & 127) + sh;
                    const AT* src = (reg == 0) ? (A + (size_t)is_ * 128 + koff)
                                  : (reg == 1) ? (A + (size_t)it_ * 128 + koff)
                                               : (A2 + (size_t)gr * 128 + koff);
                    ld8f(src, va); ld8f(src + 8, va + 8);
                } else {
                    const AT* src = A + (size_t)gr * K + k0 + sh;
                    ld8f(src, va); ld8f(src + 8, va + 8);
                    if (AMODE == AM_MUL2) {
                        float vb[16];
                        const AT* s2 = A2 + (size_t)gr * K + k0 + sh;
                        ld8f(s2, vb); ld8f(s2 + 8, vb + 8);
#pragma unroll
                        for (int j = 0; j < 16; j++) va[j] *= vb[j];
                    } else if (AMODE == AM_SILU) {
#pragma unroll
                        for (int j = 0; j < 16; j++) va[j] = silu_f(va[j]);
                    }
                }
            } else {
#pragma unroll
                for (int j = 0; j < 16; j++) va[j] = 0.f;
            }
            u16x8 av0, av1;
#pragma unroll
            for (int j = 0; j < 8; j++) { av0[j] = f2bf(va[j]); av1[j] = f2bf(va[j + 8]); }
            *(u16x8*)&Als[sr * AST + sh] = av0;
            *(u16x8*)&Als[sr * AST + sh + 8] = av1;
        }

#pragma unroll
        for (int i = 0; i < BN / 64; i++) {
            const int c = i * 256 + tid;
            gll16(Bt + (size_t)(col0 + (c >> 2)) * K + k0 + (c & 3) * 8, &Bls[c * 8]);
        }

        __syncthreads();

        short8v af[FM], bfr[4];
#pragma unroll
        for (int fm = 0; fm < FM; fm++)
            af[fm] = *(const short8v*)&Als[(wrow + fm * 16 + lr) * AST + lk];
#pragma unroll
        for (int fn = 0; fn < 4; fn++)
            bfr[fn] = *(const short8v*)&Bls[(wcol + fn * 16 + lr) * 32 + lk];
#pragma unroll
        for (int fm = 0; fm < FM; fm++)
#pragma unroll
            for (int fn = 0; fn < 4; fn++)
                acc[fm][fn] = __builtin_amdgcn_mfma_f32_16x16x32_bf16(
                    af[fm], bfr[fn], acc[fm][fn], 0, 0, 0);

        __syncthreads();
    }

#pragma unroll
    for (int fm = 0; fm < FM; fm++) {
        const int rb = row0 + wrow + fm * 16 + (l >> 4) * 4;
#pragma unroll
        for (int fn = 0; fn < 4; fn++) {
            const int c = col0 + wcol + fn * 16 + lr;
#pragma unroll
            for (int r = 0; r < 4; r++) {
                const int rr = rb + r;
                if (rr >= Mrows) continue;
                const size_t o = (size_t)rr * Ncols + c;
                stF(&C[o], epi_val(EPI, acc[fm][fn][r],
                                   (EPI >= EP_ACCUM) ? toF(C[o]) : 0.f,
                                   (EPI == EP_RESADD || EPI == EP_HEADRES) ? toF(X[o]) : 0.f));
            }
        }
    }
}

// ---------------- wide mgemm2: BM=128 x BN=256, 512 threads, PERSISTENT ----------------
// NEW (R16): epilogue routes C through LDS so all C reads/writes are 16B/lane
// coalesced (tests the sub-line-write HBM-RMW theory behind the 1.5 TB/s wall).
template <int AMODE, int EPI, typename AT, typename CT>
__global__ __launch_bounds__(512) void mgemm2(
    const AT* __restrict__ A, const AT* __restrict__ A2,
    const int* __restrict__ gs, const int* __restrict__ gt,
    const bf16* __restrict__ Bt,
    CT* __restrict__ C, const CT* __restrict__ X,
    int Mrows, int K)
{
    constexpr bool DMA = (AMODE == AM_DMA);
    constexpr int AST = DMA ? 32 : 40;
    __shared__ __align__(16) unsigned short Als[2][128 * AST];
    __shared__ __align__(16) unsigned short Bls[2][256 * 32];
    const int tid = threadIdx.x;

    const int l = tid & 63, wid = tid >> 6;
    const int lr = l & 15;
    const int lk = (l >> 4) * 8;
    const int wrow = (wid & 1) * 64;
    const int wcol = (wid >> 1) * 64;

    const int ntiles = (Mrows + 127) >> 7;

    for (int t = blockIdx.x; t < ntiles; t += gridDim.x) {
        const int row0 = t * 128;
        const int sr = tid >> 2;
        const int sh = (tid & 3) * 8;
        const int gr = row0 + sr;
        const bool rok = (gr < Mrows);
        int is_ = 0, it_ = 0;
        if (AMODE == AM_GATHER) { if (rok) { is_ = gs[gr]; it_ = gt[gr]; } }

        f32x4 acc[4][4];
#pragma unroll
        for (int i = 0; i < 4; i++)
#pragma unroll
            for (int j = 0; j < 4; j++)
#pragma unroll
                for (int q = 0; q < 4; q++) acc[i][j][q] = 0.f;

        for (int k0 = 0; k0 < K; k0 += 64) {
            float va0[8], va1[8];
#pragma unroll
            for (int h = 0; h < 2; h++) {
                const int kk = k0 + h * 32;
                if constexpr (DMA) {
                    const int row = tid >> 2;
                    if (row0 + row < Mrows)
                        gll16(A + (size_t)(row0 + row) * K + kk + (tid & 3) * 8, &Als[h][tid * 8]);
                } else {
                    float* va = h ? va1 : va0;
                    if (rok) {
                        if (AMODE == AM_GATHER) {
                            const int reg = kk >> 7, koff = (kk & 127) + sh;
                            const AT* src = (reg == 0) ? (A + (size_t)is_ * 128 + koff)
                                          : (reg == 1) ? (A + (size_t)it_ * 128 + koff)
                                                       : (A2 + (size_t)gr * 128 + koff);
                            ld8f(src, va);
                        } else {
                            ld8f(A + (size_t)gr * K + kk + sh, va);
                            if (AMODE == AM_MUL2) {
                                float vb[8];
                                ld8f(A2 + (size_t)gr * K + kk + sh, vb);
#pragma unroll
                                for (int j = 0; j < 8; j++) va[j] *= vb[j];
                            } else if (AMODE == AM_SILU) {
#pragma unroll
                                for (int j = 0; j < 8; j++) va[j] = silu_f(va[j]);
                            }
                        }
                    } else {
#pragma unroll
                        for (int j = 0; j < 8; j++) va[j] = 0.f;
                    }
                }
#pragma unroll
                for (int i = 0; i < 2; i++) {
                    const int c = i * 512 + tid;
                    gll16(Bt + (size_t)(c >> 2) * K + kk + (c & 3) * 8, &Bls[h][c * 8]);
                }
            }
            if constexpr (!DMA) {
                u16x8 av0, av1;
#pragma unroll
                for (int j = 0; j < 8; j++) { av0[j] = f2bf(va0[j]); av1[j] = f2bf(va1[j]); }
                *(u16x8*)&Als[0][sr * AST + sh] = av0;
                *(u16x8*)&Als[1][sr * AST + sh] = av1;
            }

            __syncthreads();

#pragma unroll
            for (int h = 0; h < 2; h++) {
                short8v af[4], bfr[4];
#pragma unroll
                for (int fm = 0; fm < 4; fm++)
                    af[fm] = *(const short8v*)&Als[h][(wrow + fm * 16 + lr) * AST + lk];
#pragma unroll
                for (int fn = 0; fn < 4; fn++)
                    bfr[fn] = *(const short8v*)&Bls[h][(wcol + fn * 16 + lr) * 32 + lk];
#pragma unroll
                for (int fm = 0; fm < 4; fm++)
#pragma unroll
                    for (int fn = 0; fn < 4; fn++)
                        acc[fm][fn] = __builtin_amdgcn_mfma_f32_16x16x32_bf16(
                            af[fm], bfr[fn], acc[fm][fn], 0, 0, 0);
            }

            __syncthreads();
        }

        // ---- epilogue via LDS: all global C/X I/O is u16x8 (16B/lane) ----
        unsigned short* Cs = &Bls[0][0];           // 32 KB = 64 rows x 256 cols
#pragma unroll
        for (int half = 0; half < 2; half++) {
            if (half == 1) __syncthreads();        // prev half's reads done
            if ((wid & 1) == half) {
#pragma unroll
                for (int fm = 0; fm < 4; fm++) {
                    const int rl0 = fm * 16 + (l >> 4) * 4;
#pragma unroll
                    for (int fn = 0; fn < 4; fn++) {
                        const int c = wcol + fn * 16 + lr;
#pragma unroll
                        for (int q = 0; q < 4; q++) {
                            const int r = rl0 + q;
                            Cs[r * 256 + (c ^ ((r & 3) << 3))] = f2bf(acc[fm][fn][q]);
                        }
                    }
                }
            }
            __syncthreads();
#pragma unroll
            for (int pass = 0; pass < 4; pass++) {
                const int r = pass * 16 + (tid >> 5);
                const int oct = tid & 31;
                const int rg = row0 + half * 64 + r;
                if (rg < Mrows) {
                    const u16x8 v = *(const u16x8*)&Cs[r * 256 + ((oct * 8) ^ ((r & 3) << 3))];
                    const size_t o = (size_t)rg * 256 + oct * 8;
                    u16x8 cv, xv, ov;
                    if (EPI >= EP_ACCUM) cv = *(const u16x8*)&C[o];
                    if (EPI == EP_RESADD || EPI == EP_HEADRES) xv = *(const u16x8*)&X[o];
#pragma unroll
                    for (int j = 0; j < 8; j++)
                        ov[j] = f2bf(epi_val(EPI, bf2f(v[j]),
                                             (EPI >= EP_ACCUM) ? bf2f(cv[j]) : 0.f,
                                             (EPI == EP_RESADD || EPI == EP_HEADRES) ? bf2f(xv[j]) : 0.f));
                    *(u16x8*)&C[o] = ov;
                }
            }
        }
        __syncthreads();   // protect Cs (=Bls) from next tile's staging
    }
}

// ---------------- fused triplet GEMM ----------------
__global__ __launch_bounds__(256) void trip_gemm(
    const bf16* __restrict__ x,     // [E,64]
    const bf16* __restrict__ cb,    // [T,16]
    const int* __restrict__ ba, const int* __restrict__ ca,
    const bf16* __restrict__ BtT,   // [64][1024]
    float* __restrict__ agg)
{
    __shared__ __align__(16) unsigned short At[128 * 40];
    __shared__ __align__(16) unsigned short Bs[64 * 40];
    const int tid = threadIdx.x;
    const int gr0 = blockIdx.x * 128;

    const int sr = tid >> 1, sh = tid & 1;
    const int gr = gr0 + sr;
    const int e = ba[gr];
    float xr[32];
    {
        const bf16* xp = x + (size_t)e * 64 + sh * 16;
        const u16x8 a0 = *(const u16x8*)xp;
        const u16x8 a1 = *(const u16x8*)(xp + 8);
        const u16x8 b0 = *(const u16x8*)(xp + 32);
        const u16x8 b1 = *(const u16x8*)(xp + 40);
#pragma unroll
        for (int j = 0; j < 8; j++) {
            xr[j] = bf2f(a0[j]); xr[8 + j] = bf2f(a1[j]);
            xr[16 + j] = bf2f(b0[j]); xr[24 + j] = bf2f(b1[j]);
        }
    }
    float cbr[16];
    {
        const u16x8 c0 = *(const u16x8*)(cb + (size_t)gr * 16);
        const u16x8 c1 = *(const u16x8*)(cb + (size_t)gr * 16 + 8);
#pragma unroll
        for (int j = 0; j < 8; j++) { cbr[j] = bf2f(c0[j]); cbr[8 + j] = bf2f(c1[j]); }
    }

    const int l = tid & 63, wv = tid >> 6;
    const int lr = l & 15, lg = l >> 4, lk = lg * 8;
    const int wrow = wv * 32;
    const int bcol = tid >> 2, bq = tid & 3;

    f32x4 acc[2][4];
#pragma unroll
    for (int i = 0; i < 2; i++)
#pragma unroll
        for (int j = 0; j < 4; j++)
#pragma unroll
            for (int q = 0; q < 4; q++) acc[i][j][q] = 0.f;

#pragma unroll 4
    for (int ks = 0; ks < 32; ++ks) {
        const float cbv = cbr[ks >> 1];
        const int ib = (ks & 1) * 16;
        u16x8 p0, p1;
#pragma unroll
        for (int j = 0; j < 8; j++) {
            p0[j] = f2bf(cbv * xr[ib + j]);
            p1[j] = f2bf(cbv * xr[ib + 8 + j]);
        }
        *(u16x8*)&At[sr * 40 + sh * 16] = p0;
        *(u16x8*)&At[sr * 40 + sh * 16 + 8] = p1;
        const u16x8 bv8 = *(const u16x8*)(BtT + (size_t)bcol * 1024 + ks * 32 + bq * 8);
        *(u16x8*)&Bs[bcol * 40 + bq * 8] = bv8;
        __syncthreads();

        short8v af[2], bf4[4];
        af[0] = *(const short8v*)&At[(wrow + lr) * 40 + lk];
        af[1] = *(const short8v*)&At[(wrow + 16 + lr) * 40 + lk];
#pragma unroll
        for (int fn = 0; fn < 4; fn++)
            bf4[fn] = *(const short8v*)&Bs[(fn * 16 + lr) * 40 + lk];
#pragma unroll
        for (int fm = 0; fm < 2; fm++)
#pragma unroll
            for (int fn = 0; fn < 4; fn++)
                acc[fm][fn] = __builtin_amdgcn_mfma_f32_16x16x32_bf16(
                    af[fm], bf4[fn], acc[fm][fn], 0, 0, 0);
        __syncthreads();
    }

#pragma unroll
    for (int fm = 0; fm < 2; fm++)
#pragma unroll
        for (int q = 0; q < 4; q++) {
            const int rr = wrow + fm * 16 + lg * 4 + q;
            const int eo = ca[gr0 + rr];
#pragma unroll
            for (int fn = 0; fn < 4; fn++)
                atomicAdd(&agg[(size_t)eo * 64 + fn * 16 + lr], acc[fm][fn][q]);
        }
}

__global__ __launch_bounds__(256) void cb16(const float* __restrict__ cbf,
                                            const float* __restrict__ Wcb,
                                            bf16* __restrict__ cb, int T)
{
    const int gid = blockIdx.x * 256 + threadIdx.x;
    const int t = gid >> 4, c = gid & 15;
    if (t >= T) return;
    const float* cr = cbf + (size_t)t * 7;
    float s = 0.f;
#pragma unroll
    for (int k = 0; k < 7; k++) s += cr[k] * Wcb[k * 16 + c];
    cb[(size_t)t * 16 + c] = __float2bfloat16(s);
}

struct TJob { const float* src; bf16* dst; int K; int N; };
struct TJobs { TJob j[40]; };

__global__ __launch_bounds__(256) void transpose_weights(TJobs JB) {
    const TJob J = JB.j[blockIdx.y];
    const int total = J.K * J.N;
    const int gid = blockIdx.x * 256 + threadIdx.x;
    if (gid >= total) return;
    const int n = gid / J.K, k = gid - n * J.K;
    J.dst[(size_t)n * J.K + k] = __float2bfloat16(J.src[(size_t)k * J.N + n]);
}

__global__ __launch_bounds__(256) void embed_h(const int* __restrict__ z,
                                               const float* __restrict__ tab,
                                               float* __restrict__ h, int N)
{
    const int gid = blockIdx.x * 256 + threadIdx.x;
    const int n = gid >> 7, j = gid & 127;
    if (n >= N) return;
    h[(size_t)n * 128 + j] = tab[(size_t)z[n] * 128 + j];
}

__global__ __launch_bounds__(256) void scatter_ha(const bf16* __restrict__ xa,
                                                  const int* __restrict__ idxt,
                                                  float* __restrict__ ha, int E)
{
    const int gid = blockIdx.x * 256 + threadIdx.x;
    const int e = gid >> 7, j = gid & 127;
    if (e >= E) return;
    atomicAdd(&ha[(size_t)idxt[e] * 128 + j], toF(xa[(size_t)e * 128 + j]));
}

template <typename AT>
__global__ __launch_bounds__(256) void rowdot(const AT* __restrict__ Xm,
                                              const float* __restrict__ w,
                                              float* __restrict__ outv,
                                              int rows, int width, int ostride)
{
    const int wid = (blockIdx.x * 256 + threadIdx.x) >> 6;
    const int lane = threadIdx.x & 63;
    if (wid >= rows) return;
    float s = 0.f;
    for (int q = lane; q < width; q += 64) s += toF(Xm[(size_t)wid * width + q]) * w[q];
#pragma unroll
    for (int off = 32; off > 0; off >>= 1) s += __shfl_down(s, off);
    if (lane == 0) outv[(size_t)wid * ostride] = s;
}

__global__ __launch_bounds__(256) void scatter_forces(const float* __restrict__ Fe,
                                                      const float* __restrict__ Vst,
                                                      const int* __restrict__ idxt,
                                                      float* __restrict__ out, int E)
{
    const int e = blockIdx.x * 256 + threadIdx.x;
    if (e >= E) return;
    const float f = Fe[e];
    const int n = idxt[e];
    atomicAdd(&out[(size_t)n * 4 + 1], f * Vst[(size_t)e * 3 + 0]);
    atomicAdd(&out[(size_t)n * 4 + 2], f * Vst[(size_t)e * 3 + 1]);
    atomicAdd(&out[(size_t)n * 4 + 3], f * Vst[(size_t)e * 3 + 2]);
}

#define MG(AM, EP, BNv, Aptr, A2p, GS, GT, Btp, Cp, Xp, MR, NC, KK)                       \
    mgemm<AM, EP, BNv><<<dim3(((MR) + 127) / 128, (NC) / (BNv)), 256, 0, stream>>>(       \
        Aptr, A2p, GS, GT, Btp, Cp, Xp, MR, NC, KK)

#define MG2(AM, EP, Aptr, A2p, GS, GT, Btp, Cp, Xp, MR, KK)                               \
    mgemm2<AM, EP><<<(((MR) + 127) / 128 < 1024 ? ((MR) + 127) / 128 : 1024),             \
                    512, 0, stream>>>(Aptr, A2p, GS, GT, Btp, Cp, Xp, MR, KK)

extern "C" void kernel_launch(void* const* d_in, const int* in_sizes, int n_in,
                              void* d_out, int out_size, void* d_ws, size_t ws_size,
                              hipStream_t stream)
{
    const int N = in_sizes[0];
    const int E = in_sizes[1];
    const int T = in_sizes[3];
    const int NB = 2;

    const int*   z        = (const int*)d_in[0];
    const int*   idx_s    = (const int*)d_in[1];
    const int*   idx_t    = (const int*)d_in[2];
    const int*   id3_ba   = (const int*)d_in[3];
    const int*   id3_ca   = (const int*)d_in[4];
    const float* rbf      = (const float*)d_in[5];
    const float* cbf      = (const float*)d_in[6];
    const float* V_st     = (const float*)d_in[7];
    const float* atom_tab = (const float*)d_in[8];
    const float* W_edge_in= (const float*)d_in[9];
    const float* rbf_w3   = (const float*)d_in[10];
    const float* W_down   = (const float*)d_in[11];
    const float* W_cbf    = (const float*)d_in[12];
    const float* W_bil    = (const float*)d_in[13];
    const float* W_up     = (const float*)d_in[14];
    const float* W_res_e  = (const float*)d_in[15];
    const float* rbf_wh   = (const float*)d_in[16];
    const float* W_e2a    = (const float*)d_in[17];
    const float* W_res_a  = (const float*)d_in[18];
    const float* W_outE_in  = (const float*)d_in[19];
    const float* W_outE_res = (const float*)d_in[20];
    const float* W_outE_fin = (const float*)d_in[21];
    const float* W_outF_in  = (const float*)d_in[22];
    const float* W_outF_res = (const float*)d_in[23];
    const float* W_outF_fin = (const float*)d_in[24];

    float* out = (float*)d_out;

    // ---- workspace layout ----
    char* base = (char*)d_ws;
    size_t off = 0;
    auto alloc = [&](size_t nbytes) { char* p = base + off; off += (nbytes + 15) & ~(size_t)15; return p; };
    bf16*  m_cur = (bf16*)alloc((size_t)E * 256 * 2);
    bf16*  headF = (bf16*)alloc((size_t)E * 256 * 2);
    bf16*  S1    = (bf16*)alloc((size_t)E * 256 * 2);
    float* agg   = (float*)alloc((size_t)E * 64 * 4);
    bf16*  xbuf  = (bf16*)alloc((size_t)E * 64 * 2);
    float* h_cur = (float*)alloc((size_t)N * 128 * 4);
    float* headE = (float*)alloc((size_t)N * 128 * 4);
    float* ha    = (float*)alloc((size_t)N * 128 * 4);
    float* tA    = (float*)alloc((size_t)N * 128 * 4);
    bf16 *bt_outF[3], *bt_outE[3], *bt_r3[2], *bt_down[2], *bt_bilT[2], *bt_up[2],
         *bt_rese[8], *bt_rh[2], *bt_e2a[2], *bt_resa[4], *bt_Fres[2], *bt_Eres[2];
    bf16* bt_edge = (bf16*)alloc(384 * 256 * 2);
    for (int s = 0; s < 3; s++) bt_outF[s] = (bf16*)alloc(256 * 256 * 2);
    for (int s = 0; s < 3; s++) bt_outE[s] = (bf16*)alloc(128 * 128 * 2);
    for (int b = 0; b < 2; b++) bt_r3[b]   = (bf16*)alloc(256 * 128 * 2);
    for (int b = 0; b < 2; b++) bt_down[b] = (bf16*)alloc(64 * 256 * 2);
    for (int b = 0; b < 2; b++) bt_bilT[b] = (bf16*)alloc(64 * 1024 * 2);
    for (int b = 0; b < 2; b++) bt_up[b]   = (bf16*)alloc(256 * 64 * 2);
    for (int i = 0; i < 8; i++) bt_rese[i] = (bf16*)alloc(256 * 256 * 2);
    for (int b = 0; b < 2; b++) bt_rh[b]   = (bf16*)alloc(256 * 128 * 2);
    for (int b = 0; b < 2; b++) bt_e2a[b]  = (bf16*)alloc(128 * 256 * 2);
    for (int i = 0; i < 4; i++) bt_resa[i] = (bf16*)alloc(128 * 128 * 2);
    for (int i = 0; i < 2; i++) bt_Fres[i] = (bf16*)alloc(256 * 256 * 2);
    for (int i = 0; i < 2; i++) bt_Eres[i] = (bf16*)alloc(128 * 128 * 2);
    if (off > ws_size) {
        fprintf(stderr, "kernel_launch: ws too small: need %zu have %zu\n", off, ws_size);
        return;
    }
    bf16*  xa = (bf16*)agg;    // [E,128] bf16, agg region reused post-triplet
    float* Fe = (float*)xbuf;  // [E] f32 post-loop
    float* xE = ha;            // [N,128] f32 post-loop
    bf16*  cbS = S1;           // [T,16] bf16 during triplet

    const float* nfp = nullptr;
    const bf16*  nbp = nullptr;
    const int*   nip = nullptr;

    // ---- weight transposes ----
    {
        TJobs JB; int nj = 0;
        auto addj = [&](const float* s, bf16* d, int K, int Nn) { JB.j[nj++] = TJob{s, d, K, Nn}; };
        addj(W_edge_in, bt_edge, 384, 256);
        for (int s = 0; s < 3; s++) addj(W_outF_in + (size_t)s * 256 * 256, bt_outF[s], 256, 256);
        for (int s = 0; s < 3; s++) addj(W_outE_in + (size_t)s * 128 * 128, bt_outE[s], 128, 128);
        for (int b = 0; b < 2; b++) addj(rbf_w3 + (size_t)b * 128 * 256, bt_r3[b], 128, 256);
        for (int b = 0; b < 2; b++) addj(W_down + (size_t)b * 256 * 64, bt_down[b], 256, 64);
        for (int b = 0; b < 2; b++) addj(W_bil + (size_t)b * 65536, bt_bilT[b], 1024, 64);
        for (int b = 0; b < 2; b++) addj(W_up + (size_t)b * 64 * 256, bt_up[b], 64, 256);
        for (int i = 0; i < 8; i++) addj(W_res_e + (size_t)i * 65536, bt_rese[i], 256, 256);
        for (int b = 0; b < 2; b++) addj(rbf_wh + (size_t)b * 128 * 256, bt_rh[b], 128, 256);
        for (int b = 0; b < 2; b++) addj(W_e2a + (size_t)b * 256 * 128, bt_e2a[b], 256, 128);
        for (int i = 0; i < 4; i++) addj(W_res_a + (size_t)i * 16384, bt_resa[i], 128, 128);
        for (int i = 0; i < 2; i++) addj(W_outF_res + (size_t)i * 65536, bt_Fres[i], 256, 256);
        for (int i = 0; i < 2; i++) addj(W_outE_res + (size_t)i * 16384, bt_Eres[i], 128, 128);
        transpose_weights<<<dim3(384, nj), 256, 0, stream>>>(JB);
    }

    // h0, m0, head slice-0 accumulators
    embed_h<<<(N * 128 + 255) / 256, 256, 0, stream>>>(z, atom_tab, h_cur, N);
    MG2(AM_GATHER, EP_SILU, h_cur, rbf, idx_s, idx_t, bt_edge, m_cur, nbp, E, 384);
    MG2(AM_DMA, EP_PLAIN, m_cur, nbp, nip, nip, bt_outF[0], headF, nbp, E, 256);
    MG(AM_NORMAL, EP_PLAIN, 64, h_cur, nfp, nip, nip, bt_outE[0], headE, nfp, N, 128, 128);

    for (int b = 0; b < NB; ++b) {
        const float* Wcb = W_cbf + (size_t)b * 7 * 16;

        // --- triplet path ---
        MG2(AM_NORMAL, EP_PLAIN, rbf, nfp, nip, nip, bt_r3[b], S1, nbp, E, 128);
        MG(AM_MUL2, EP_PLAIN, 64, m_cur, S1, nip, nip, bt_down[b], xbuf, nbp, E, 64, 256);
        cb16<<<(T * 16 + 255) / 256, 256, 0, stream>>>(cbf, Wcb, cbS, T);
        (void)hipMemsetAsync(agg, 0, (size_t)E * 64 * sizeof(float), stream);
        trip_gemm<<<T / 128, 256, 0, stream>>>(xbuf, cbS, id3_ba, id3_ca, bt_bilT[b], agg);

        // --- residual part 1 ---
        MG2(AM_DMA, EP_SILU, m_cur, nbp, nip, nip, bt_rese[4 * b + 0], S1, nbp, E, 256);
        MG2(AM_DMA, EP_RES2, S1, nbp, nip, nip, bt_rese[4 * b + 1], m_cur, nbp, E, 256);
        // --- inject x3 ---
        MG2(AM_NORMAL, EP_RES2, agg, nfp, nip, nip, bt_up[b], m_cur, nbp, E, 64);
        // --- residual part 2 ---
        MG2(AM_DMA, EP_SILU, m_cur, nbp, nip, nip, bt_rese[4 * b + 2], S1, nbp, E, 256);
        MG2(AM_DMA, EP_RES2, S1, nbp, nip, nip, bt_rese[4 * b + 3], m_cur, nbp, E, 256);
        // --- F-head accumulator ---
        MG2(AM_DMA, EP_ACCUM, m_cur, nbp, nip, nip, bt_outF[b + 1], headF, nbp, E, 256);

        // --- atom update ---
        MG2(AM_NORMAL, EP_PLAIN, rbf, nfp, nip, nip, bt_rh[b], S1, nbp, E, 128);
        MG(AM_MUL2, EP_PLAIN, 128, m_cur, S1, nip, nip, bt_e2a[b], xa, nbp, E, 128, 256);
        (void)hipMemsetAsync(ha, 0, (size_t)N * 128 * sizeof(float), stream);
        scatter_ha<<<(E * 128 + 255) / 256, 256, 0, stream>>>(xa, idx_t, ha, E);
        MG(AM_NORMAL, EP_SILU, 64, ha, nfp, nip, nip, bt_resa[2 * b + 0], tA, nfp, N, 128, 128);
        MG(AM_NORMAL, EP_RESADD, 64, tA, nfp, nip, nip, bt_resa[2 * b + 1], h_cur, ha, N, 128, 128);
        MG(AM_NORMAL, EP_ACCUM, 64, h_cur, nfp, nip, nip, bt_outE[b + 1], headE, nfp, N, 128, 128);
    }

    // --- F head ---
    MG2(AM_SILU, EP_SILU, headF, nbp, nip, nip, bt_Fres[0], S1, nbp, E, 256);
    MG2(AM_DMA, EP_HEADRES, S1, nbp, nip, nip, bt_Fres[1], m_cur, headF, E, 256);
    rowdot<<<(E * 64 + 255) / 256, 256, 0, stream>>>(m_cur, W_outF_fin, Fe, E, 256, 1);

    // --- E head + output ---
    (void)hipMemsetAsync(out, 0, (size_t)out_size * sizeof(float), stream);
    MG(AM_SILU, EP_SILU, 64, headE, nfp, nip, nip, bt_Eres[0], tA, nfp, N, 128, 128);
    MG(AM_NORMAL, EP_HEADRES, 64, tA, nfp, nip, nip, bt_Eres[1], xE, headE, N, 128, 128);
    rowdot<<<(N * 64 + 255) / 256, 256, 0, stream>>>(xE, W_outE_fin, out, N, 128, 4);
    scatter_forces<<<(E + 255) / 256, 256, 0, stream>>>(Fe, V_st, idx_t, out, E);
}